// Round 6
// baseline (26031.219 us; speedup 1.0000x reference)
//
#include <hip/hip_runtime.h>
#include <math.h>

// Problem: B=8192, NH=128, M=4096, XD=1024
#define ALPHA_1 100.0f
#define SIGMA_1 0.02f

typedef unsigned short bf16_t;   // raw bf16 storage
typedef short  bf16x8  __attribute__((ext_vector_type(8)));   // MFMA A/B frag
typedef float  floatx4 __attribute__((ext_vector_type(4)));   // MFMA C/D frag

typedef __attribute__((address_space(1))) void glb_void;
typedef __attribute__((address_space(3))) void lds_void;

__device__ __forceinline__ float bf2f(bf16_t u){ return __uint_as_float(((unsigned)u)<<16); }
__device__ __forceinline__ bf16_t f2bf(float f){
  unsigned u = __float_as_uint(f);
  u += 0x7FFFu + ((u>>16)&1u);          // RNE
  return (bf16_t)(u>>16);
}

// split float4 -> bf16 hi + bf16 residual lo
__device__ __forceinline__ void split4(float4 v, ushort4& h, ushort4& l){
  h.x=f2bf(v.x); h.y=f2bf(v.y); h.z=f2bf(v.z); h.w=f2bf(v.w);
  l.x=f2bf(v.x-bf2f(h.x)); l.y=f2bf(v.y-bf2f(h.y));
  l.z=f2bf(v.z-bf2f(h.z)); l.w=f2bf(v.w-bf2f(h.w));
}

__device__ __forceinline__ float4 load4f(const float* p){ return *(const float4*)p; }
__device__ __forceinline__ float loadS(const float* p){ return *p; }
__device__ __forceinline__ float loadS(const bf16_t* p){ return bf2f(*p); }
__device__ __forceinline__ void storeS(float* p, float v){ *p = v; }
__device__ __forceinline__ void storeS(bf16_t* p, float v){ *p = f2bf(v); }

// async 16B global->LDS (gfx950). LDS side is wave-uniform base + lane*16.
__device__ __forceinline__ void async_copy16(void* lds, const void* g){
  __builtin_amdgcn_global_load_lds((glb_void*)g, (lds_void*)lds, 16, 0, 0);
}

// ---------------------------------------------------------------------------
// bf16 MFMA NT GEMM (forward path): C[M][N] = sum_k A[m][k]*B[n][k] + bias.
// 128x128 tile, BK=64, 4 waves of 64x64. NO XCD swizzle: operands are
// L3-resident and chunked swizzle doubled FETCH_SIZE (round-5 measurement).
// ---------------------------------------------------------------------------
template<typename TC, int RELU>
__global__ __launch_bounds__(256) void mfma_nt_kernel(
    int Mm, int Nn, int Kk,
    const bf16_t* __restrict__ A, int lda,
    const bf16_t* __restrict__ B, int ldb,
    TC* __restrict__ C, int ldc,
    const float* __restrict__ bias)
{
  __shared__ bf16_t As[128*64];
  __shared__ bf16_t Bs[128*64];
  const int tid  = threadIdx.x;
  const int lane = tid & 63, wv = tid >> 6;
  const int m0 = (int)(blockIdx.y << 7), n0 = (int)(blockIdx.x << 7);
  const int wm = (wv >> 1) << 6, wn = (wv & 1) << 6;
  const int rbase = wv << 5;                 // 32 rows per wave

  floatx4 acc[4][4] = {};

  for (int kk = 0; kk < Kk; kk += 64){
    __syncthreads();                         // prev iter's readers done
#pragma unroll
    for (int q=0;q<4;q++){
      int row = rbase + (q<<3) + (lane>>3);
      int cg  = (lane&7) ^ (row&7);          // swizzled global chunk
      async_copy16(&As[(size_t)(rbase+(q<<3))<<6],
                   A + (size_t)(m0+row)*lda + kk + (cg<<3));
      async_copy16(&Bs[(size_t)(rbase+(q<<3))<<6],
                   B + (size_t)(n0+row)*ldb + kk + (cg<<3));
    }
    __syncthreads();
#pragma unroll
    for (int ks=0; ks<2; ks++){
      bf16x8 af[4], bf[4];
      int quad = lane>>4, mr = lane&15;
      int c = quad + (ks<<2);                // chunk 0..7
#pragma unroll
      for (int i=0;i<4;i++){
        int rowa = wm + i*16 + mr;
        af[i] = *(const bf16x8*)&As[(rowa<<6) + ((c ^ (rowa&7))<<3)];
        int rowb = wn + i*16 + mr;
        bf[i] = *(const bf16x8*)&Bs[(rowb<<6) + ((c ^ (rowb&7))<<3)];
      }
#pragma unroll
      for (int i=0;i<4;i++)
#pragma unroll
        for (int j=0;j<4;j++)
          acc[i][j] = __builtin_amdgcn_mfma_f32_16x16x32_bf16(af[i], bf[j], acc[i][j], 0,0,0);
    }
  }
#pragma unroll
  for (int i=0;i<4;i++){
#pragma unroll
    for (int j=0;j<4;j++){
      int rbase2 = m0 + wm + i*16 + (lane>>4)*4;
      int col    = n0 + wn + j*16 + (lane&15);
      float bv = bias ? bias[col] : 0.0f;
#pragma unroll
      for (int r=0;r<4;r++){
        float v = acc[i][j][r] + bv;
        if (RELU) v = fmaxf(v, 0.0f);
        storeS(&C[(size_t)(rbase2+r)*ldc + col], v);
      }
    }
  }
}

// ---------------------------------------------------------------------------
// fp32-precision NT GEMM on matrix cores via bf16 hi/lo split (bf16x3):
// C[M][N] = alpha*(aptr?)*sum_k A[m][k]*Bt[n][k] + beta*C. 128x128 tile, BK=64.
// ---------------------------------------------------------------------------
template<typename TC>
__global__ __launch_bounds__(256) void fgemm_nt_kernel(
    int Mm, int Nn, int Kk,
    const float* __restrict__ A, int lda,
    const float* __restrict__ Bt, int ldb,
    TC* __restrict__ C, int ldc,
    float alpha, const float* __restrict__ alpha_ptr, float beta, int skipk)
{
  __shared__ bf16_t Ah[128*64], Al[128*64], Bh[128*64], Bl[128*64];
  const int tid = threadIdx.x;
  const int lane = tid & 63, wv = tid >> 6;
  int by = blockIdx.y; if (by >= skipk) by++;
  const int m0 = by << 7, n0 = blockIdx.x << 7;
  const int wm = (wv >> 1) << 6, wn = (wv & 1) << 6;
  floatx4 acc[4][4] = {};

  for (int kk = 0; kk < Kk; kk += 64){
    float4 va[8], vb[8];
#pragma unroll
    for (int i=0;i<8;i++){
      int idx = (tid<<3) + i;               // 0..2047
      int row = idx >> 4;                   // 0..127
      int cg  = idx & 15;                   // float4 granule
      va[i] = load4f(A  + (size_t)(m0+row)*lda + kk + (cg<<2));
      vb[i] = load4f(Bt + (size_t)(n0+row)*ldb + kk + (cg<<2));
    }
    __syncthreads();
#pragma unroll
    for (int i=0;i<8;i++){
      int idx = (tid<<3) + i;
      int row = idx >> 4, cg = idx & 15;
      int off = (row<<6) + (((cg>>1) ^ (row&7))<<3) + ((cg&1)<<2);
      ushort4 hv, lv; split4(va[i], hv, lv);
      *(ushort4*)&Ah[off] = hv; *(ushort4*)&Al[off] = lv;
      ushort4 hw, lw; split4(vb[i], hw, lw);
      *(ushort4*)&Bh[off] = hw; *(ushort4*)&Bl[off] = lw;
    }
    __syncthreads();
#pragma unroll
    for (int ks=0; ks<2; ks++){
      int quad = lane>>4, mr = lane&15;
      int c = quad + (ks<<2);
      bf16x8 ah[4], al[4], bh[4], bl[4];
#pragma unroll
      for (int i=0;i<4;i++){
        int rowa = wm + i*16 + mr; int sa = (rowa<<6) + ((c ^ (rowa&7))<<3);
        ah[i] = *(const bf16x8*)&Ah[sa]; al[i] = *(const bf16x8*)&Al[sa];
        int rowb = wn + i*16 + mr; int sb = (rowb<<6) + ((c ^ (rowb&7))<<3);
        bh[i] = *(const bf16x8*)&Bh[sb]; bl[i] = *(const bf16x8*)&Bl[sb];
      }
#pragma unroll
      for (int i=0;i<4;i++)
#pragma unroll
        for (int j=0;j<4;j++){
          acc[i][j] = __builtin_amdgcn_mfma_f32_16x16x32_bf16(ah[i], bl[j], acc[i][j], 0,0,0);
          acc[i][j] = __builtin_amdgcn_mfma_f32_16x16x32_bf16(al[i], bh[j], acc[i][j], 0,0,0);
          acc[i][j] = __builtin_amdgcn_mfma_f32_16x16x32_bf16(ah[i], bh[j], acc[i][j], 0,0,0);
        }
    }
    __syncthreads();
  }
  float am = alpha;
  if (alpha_ptr) am *= *alpha_ptr;
#pragma unroll
  for (int i=0;i<4;i++){
#pragma unroll
    for (int j=0;j<4;j++){
      int rb = m0 + wm + i*16 + (lane>>4)*4;
      int col = n0 + wn + j*16 + (lane&15);
#pragma unroll
      for (int r=0;r<4;r++){
        size_t off = (size_t)(rb+r)*ldc + col;
        float v = am * acc[i][j][r];
        if (beta != 0.0f) v = fmaf(beta, loadS(&C[off]), v);
        storeS(&C[off], v);
      }
    }
  }
}

// ---------------------------------------------------------------------------
// 128x128 Gauss-Jordan inverse (no pivot), 1024 threads, register-resident.
// Writes inverse AND its transpose. (Used standalone by phases 2/3.)
// ---------------------------------------------------------------------------
__global__ __launch_bounds__(1024) void invert128_kernel(
    const float* __restrict__ src, int ld,
    float* __restrict__ dst, float* __restrict__ dstT)
{
  __shared__ float brow[2][8*36];            // [parity][sub*36 + col]
  const int t = threadIdx.x;
  const int r = t>>3, sub = t&7;
  const int lane = t & 63;
  const int cb = (sub&3)<<5;
  const bool isA = sub < 4;
  float own[32];
  if (isA){
#pragma unroll
    for (int i=0;i<32;i++) own[i] = src[(size_t)r*ld + cb + i];
  } else {
#pragma unroll
    for (int i=0;i<32;i++) own[i] = (cb+i == r) ? 1.0f : 0.0f;
  }
  for (int pb=0; pb<4; pb++){
#pragma unroll
    for (int pi=0; pi<32; pi++){
      const int p = (pb<<5) + pi;
      float f = __shfl(own[pi], (lane & 56) | pb);
      float* bw = brow[p & 1];
      if (r == p){
        float ip = 1.0f / f;
#pragma unroll
        for (int i=0;i<32;i++) own[i] *= ip;
#pragma unroll
        for (int i=0;i<8;i++){
          float4 v;
          v.x = own[(i<<2)+0]; v.y = own[(i<<2)+1];
          v.z = own[(i<<2)+2]; v.w = own[(i<<2)+3];
          *(float4*)&bw[sub*36 + (i<<2)] = v;
        }
      }
      __syncthreads();
      if (r != p){
#pragma unroll
        for (int i=0;i<8;i++){
          float4 b = *(const float4*)&bw[sub*36 + (i<<2)];
          own[(i<<2)+0] = fmaf(-f, b.x, own[(i<<2)+0]);
          own[(i<<2)+1] = fmaf(-f, b.y, own[(i<<2)+1]);
          own[(i<<2)+2] = fmaf(-f, b.z, own[(i<<2)+2]);
          own[(i<<2)+3] = fmaf(-f, b.w, own[(i<<2)+3]);
        }
      }
    }
  }
  if (!isA){
#pragma unroll
    for (int i=0;i<32;i++){
      dst [(size_t)r*128 + cb + i] = own[i];
      dstT[(size_t)(cb+i)*128 + r] = own[i];
    }
  }
}

// ===========================================================================
// Block Gauss-Jordan inverse: round-4 overlap topology + fast 256-thr prep.
// Per step k (2 plain dispatches, ping-pong Min -> Mout):
//   stepA (2nb-1 blocks): update only col k+1 and row k+1 tiles.
//   stepB (nb + (nb-1)^2 blocks): blocks [0,nb) run prep_fast(k+1) reading
//     Mout's fresh col/row k+1 (stepA output, previous dispatch); remaining
//     blocks update the rest. Disjoint reads/writes, no intra-dispatch dep.
// G,T pre-split bf16 hi/lo; PTs scratch is PER-BLOCK (no write contention).
// All LDS <= 32KB so update occupancy stays high in the fused dispatch.
// ===========================================================================

// stage 128x32 slab of fp32 (ld ldg, col offset koff) -> swizzled bf16 hi/lo
__device__ __forceinline__ void stage_f32_chunk(
    const float* __restrict__ g, int ldg, int koff,
    bf16_t* Hh, bf16_t* Hl, int tid)
{
#pragma unroll
  for (int q=0;q<4;q++){
    int f4 = (tid<<2)+q;                  // 0..1023
    int row = f4>>3, cg4 = f4&7;          // 8 float4 per row
    float4 v = *(const float4*)&g[(size_t)row*ldg + koff + (cg4<<2)];
    int off = (row<<5) + (((cg4>>1) ^ (row&3))<<3) + ((cg4&1)<<2);
    ushort4 hv, lv; split4(v, hv, lv);
    *(ushort4*)&Hh[off]=hv; *(ushort4*)&Hl[off]=lv;
  }
}

// stage 128x32 slab of pre-split bf16 [128][128] row-major, col offset kk
__device__ __forceinline__ void stage_bf16_chunk(
    const bf16_t* __restrict__ gh, const bf16_t* __restrict__ gl, int kk,
    bf16_t* Hh, bf16_t* Hl, int tid)
{
#pragma unroll
  for (int q=0;q<4;q++){
    int f4 = (tid<<2)+q;
    int row = f4>>3, cg4 = f4&7;
    ushort4 hv = *(const ushort4*)&gh[(row<<7) + kk + (cg4<<2)];
    ushort4 lv = *(const ushort4*)&gl[(row<<7) + kk + (cg4<<2)];
    int off = (row<<5) + (((cg4>>1) ^ (row&3))<<3) + ((cg4&1)<<2);
    *(ushort4*)&Hh[off]=hv; *(ushort4*)&Hl[off]=lv;
  }
}

// one 32-K chunk of bf16x3 MFMA from swizzled LDS tiles (32 bf16 per row)
__device__ __forceinline__ void mfma_chunk(
    const bf16_t* Ah, const bf16_t* Al, const bf16_t* Bh, const bf16_t* Bl,
    int lane, int wm, int wn, floatx4 acc[4][4])
{
  int quad = lane>>4, mr = lane&15;
  bf16x8 ah[4], al[4], bh[4], bl[4];
#pragma unroll
  for (int i=0;i<4;i++){
    int rowa = wm + i*16 + mr; int sa = (rowa<<5) + ((quad ^ (rowa&3))<<3);
    ah[i] = *(const bf16x8*)&Ah[sa]; al[i] = *(const bf16x8*)&Al[sa];
    int rowb = wn + i*16 + mr; int sb = (rowb<<5) + ((quad ^ (rowb&3))<<3);
    bh[i] = *(const bf16x8*)&Bh[sb]; bl[i] = *(const bf16x8*)&Bl[sb];
  }
#pragma unroll
  for (int i=0;i<4;i++)
#pragma unroll
    for (int j=0;j<4;j++){
      acc[i][j] = __builtin_amdgcn_mfma_f32_16x16x32_bf16(ah[i], bl[j], acc[i][j], 0,0,0);
      acc[i][j] = __builtin_amdgcn_mfma_f32_16x16x32_bf16(al[i], bh[j], acc[i][j], 0,0,0);
      acc[i][j] = __builtin_amdgcn_mfma_f32_16x16x32_bf16(ah[i], bh[j], acc[i][j], 0,0,0);
    }
}

// update one tile:  Mout(by,bx) = (bx==k) ? G[by] : (by!=k)*Min + G[by]*T[bx]^T
__device__ void update_tile(
    const float* __restrict__ Min, float* __restrict__ Mout, int n, int k,
    int by, int bx,
    const bf16_t* __restrict__ Gh, const bf16_t* __restrict__ Gl,
    const bf16_t* __restrict__ Th, const bf16_t* __restrict__ Tl,
    char* sm, int tid)
{
  if (bx == k){
    const bf16_t* sh = Gh + ((size_t)by<<14);
    const bf16_t* sl = Gl + ((size_t)by<<14);
    float* dst = Mout + ((size_t)(by<<7))*n + ((size_t)k<<7);
    for (int q=tid; q<4096; q+=256){
      int r=q>>5, c4=(q&31)<<2;
      ushort4 hv=*(const ushort4*)&sh[(r<<7)+c4];
      ushort4 lv=*(const ushort4*)&sl[(r<<7)+c4];
      float4 v; v.x=bf2f(hv.x)+bf2f(lv.x); v.y=bf2f(hv.y)+bf2f(lv.y);
                v.z=bf2f(hv.z)+bf2f(lv.z); v.w=bf2f(hv.w)+bf2f(lv.w);
      *(float4*)&dst[(size_t)r*n + c4] = v;
    }
    return;
  }
  bf16_t* Ah=(bf16_t*)sm; bf16_t* Al=(bf16_t*)(sm+8192);
  bf16_t* Bh=(bf16_t*)(sm+16384); bf16_t* Bl=(bf16_t*)(sm+24576);
  const int lane=tid&63, wv=tid>>6, wm=(wv>>1)<<6, wn=(wv&1)<<6;
  const bf16_t* gh = Gh + ((size_t)by<<14);
  const bf16_t* gl = Gl + ((size_t)by<<14);
  const bf16_t* th = Th + ((size_t)bx<<14);
  const bf16_t* tl = Tl + ((size_t)bx<<14);
  floatx4 acc[4][4] = {};
#pragma unroll
  for (int kk=0; kk<128; kk+=32){
    __syncthreads();
    stage_bf16_chunk(gh, gl, kk, Ah, Al, tid);
    stage_bf16_chunk(th, tl, kk, Bh, Bl, tid);
    __syncthreads();
    mfma_chunk(Ah, Al, Bh, Bl, lane, wm, wn, acc);
  }
  const int addin = (by != k);
#pragma unroll
  for (int i=0;i<4;i++)
#pragma unroll
    for (int j=0;j<4;j++){
      int rb = (by<<7) + wm + i*16 + ((lane>>4)<<2);
      int col = (bx<<7) + wn + j*16 + (lane&15);
#pragma unroll
      for (int r4=0;r4<4;r4++){
        size_t off = (size_t)(rb+r4)*n + col;
        float v = acc[i][j][r4];
        if (addin) v += Min[off];
        Mout[off] = v;
      }
    }
}

// ---------------------------------------------------------------------------
// prep_fast (256 threads): in-place register GJ inverse of the pivot tile
// (2 threads/row, own[64], shfl-broadcast factor, parity float4 brow — one
// barrier/pivot); then block ib != kp writes PTs[ib] = P^T, T[ib] = M[kp][ib]^T
// (both via 32x32 LDS-transpose subtiles, coalesced ushort4 hi/lo stores) and
// G[ib] = -(M[ib][kp]*P) via bf16x3 MFMA (B from own PTs). Block kp: G[kp]=P.
// ---------------------------------------------------------------------------
__device__ void prep_fast(
    const float* __restrict__ M, int n, int kp, int ib,
    bf16_t* __restrict__ Gh, bf16_t* __restrict__ Gl,
    bf16_t* __restrict__ Th, bf16_t* __restrict__ Tl,
    bf16_t* __restrict__ PTsh, bf16_t* __restrict__ PTsl,
    char* sm, int tid)
{
  const int lane = tid & 63;
  const int r = tid >> 1, half = tid & 1;
  const float* D = M + ((size_t)(kp<<7))*n + (kp<<7);
  float own[64];
#pragma unroll
  for (int j4=0;j4<16;j4++)
    *(float4*)&own[j4<<2] = *(const float4*)&D[(size_t)r*n + (half<<6) + (j4<<2)];
  float* brow = (float*)sm;            // [2][132] floats
  for (int pb=0; pb<2; pb++){
#pragma unroll
    for (int pi=0; pi<64; pi++){
      const int p = (pb<<6) + pi;
      // f = current M[r][p], held by the half==pb thread of this row pair
      float f = __shfl(own[pi], (lane & 62) | pb);
      float* bw = brow + (p & 1)*132;
      if (r == p){
        float ip = 1.0f / f;
#pragma unroll
        for (int j=0;j<64;j++) own[j] *= ip;
        if (half == pb) own[pi] = ip;
#pragma unroll
        for (int j4=0;j4<16;j4++){
          float4 v;
          v.x=own[(j4<<2)+0]; v.y=own[(j4<<2)+1];
          v.z=own[(j4<<2)+2]; v.w=own[(j4<<2)+3];
          *(float4*)&bw[(half<<6)+(j4<<2)] = v;
        }
      }
      __syncthreads();
      if (r != p){
        float ip = bw[(pb<<6)+pi];     // scaled pivot diagonal = 1/d
#pragma unroll
        for (int j=0;j<64;j++) own[j] = fmaf(-f, bw[(half<<6)+j], own[j]);
        if (half == pb) own[pi] = -f*ip;
      }
    }
  }
  // own[] = P[r][half*64+j]
  if (ib == kp){
    bf16_t* gh = Gh + ((size_t)kp<<14);
    bf16_t* gl = Gl + ((size_t)kp<<14);
#pragma unroll
    for (int j4=0;j4<16;j4++){
      float4 v;
      v.x=own[(j4<<2)+0]; v.y=own[(j4<<2)+1];
      v.z=own[(j4<<2)+2]; v.w=own[(j4<<2)+3];
      ushort4 hv, lv; split4(v, hv, lv);
      *(ushort4*)&gh[(r<<7)+(half<<6)+(j4<<2)] = hv;
      *(ushort4*)&gl[(r<<7)+(half<<6)+(j4<<2)] = lv;
    }
    return;
  }
  // ---- PTs[ib] = P^T hi/lo via 32x32 LDS-transpose subtiles
  float* tr = (float*)sm;              // [32][36]
  bf16_t* pth = PTsh + ((size_t)ib<<14);
  bf16_t* ptl = PTsl + ((size_t)ib<<14);
#pragma unroll
  for (int sb=0; sb<16; sb++){
    const int bi = sb>>2, bj = sb&3;   // P rows bi*32.., cols bj*32..
    __syncthreads();
    if ((r>>5)==bi && half==(bj>>1)){
      int rl = r & 31, c0 = (bj&1)<<5;
#pragma unroll
      for (int j4=0;j4<8;j4++)
        *(float4*)&tr[rl*36 + (j4<<2)] = *(const float4*)&own[c0 + (j4<<2)];
    }
    __syncthreads();
    {
      int cl = tid>>3, rl4 = (tid&7)<<2;
      float4 v;
      v.x = tr[(rl4+0)*36+cl]; v.y = tr[(rl4+1)*36+cl];
      v.z = tr[(rl4+2)*36+cl]; v.w = tr[(rl4+3)*36+cl];
      ushort4 hv, lv; split4(v, hv, lv);
      int o = (((bj<<5)+cl)<<7) + (bi<<5) + rl4;
      *(ushort4*)&pth[o] = hv;
      *(ushort4*)&ptl[o] = lv;
    }
  }
  // ---- T[ib] = M[kp][ib]^T hi/lo via the same subtile path (global source)
  const float* Ski = M + ((size_t)(kp<<7))*n + (ib<<7);
  bf16_t* th = Th + ((size_t)ib<<14);
  bf16_t* tl = Tl + ((size_t)ib<<14);
#pragma unroll
  for (int sb=0; sb<16; sb++){
    const int bi = sb>>2, bj = sb&3;
    __syncthreads();
    {
      int rl = tid>>3, c4 = (tid&7)<<2;
      *(float4*)&tr[rl*36 + c4] =
        *(const float4*)&Ski[(size_t)((bi<<5)+rl)*n + (bj<<5) + c4];
    }
    __syncthreads();
    {
      int cl = tid>>3, rl4 = (tid&7)<<2;
      float4 v;
      v.x = tr[(rl4+0)*36+cl]; v.y = tr[(rl4+1)*36+cl];
      v.z = tr[(rl4+2)*36+cl]; v.w = tr[(rl4+3)*36+cl];
      ushort4 hv, lv; split4(v, hv, lv);
      int o = (((bj<<5)+cl)<<7) + (bi<<5) + rl4;
      *(ushort4*)&th[o] = hv;
      *(ushort4*)&tl[o] = lv;
    }
  }
  // ---- G[ib] = -(M[ib][kp] * P) via bf16x3 MFMA (B-operand = PTs[ib])
  {
    bf16_t* Ah=(bf16_t*)sm; bf16_t* Al=(bf16_t*)(sm+8192);
    bf16_t* Bh=(bf16_t*)(sm+16384); bf16_t* Bl=(bf16_t*)(sm+24576);
    const float* Asrc = M + ((size_t)(ib<<7))*n + (kp<<7);
    const int wv = tid>>6, wm = (wv>>1)<<6, wn = (wv&1)<<6;
    floatx4 acc[4][4] = {};
#pragma unroll
    for (int kk=0; kk<128; kk+=32){
      __syncthreads();
      stage_f32_chunk(Asrc, n, kk, Ah, Al, tid);
      stage_bf16_chunk(pth, ptl, kk, Bh, Bl, tid);
      __syncthreads();
      mfma_chunk(Ah, Al, Bh, Bl, lane, wm, wn, acc);
    }
    bf16_t* gh = Gh + ((size_t)ib<<14);
    bf16_t* gl = Gl + ((size_t)ib<<14);
#pragma unroll
    for (int i=0;i<4;i++)
#pragma unroll
      for (int j=0;j<4;j++){
        int rb = wm + i*16 + ((lane>>4)<<2);
        int col = wn + j*16 + (lane&15);
#pragma unroll
        for (int r4=0;r4<4;r4++){
          float v = -acc[i][j][r4];
          bf16_t hh = f2bf(v);
          gh[((rb+r4)<<7)+col] = hh;
          gl[((rb+r4)<<7)+col] = f2bf(v - bf2f(hh));
        }
      }
  }
}

// standalone prep(0): nb blocks
__global__ __launch_bounds__(256) void gj_prep0_kernel(
    const float* __restrict__ M, int n,
    bf16_t* Gh, bf16_t* Gl, bf16_t* Th, bf16_t* Tl,
    bf16_t* PTsh, bf16_t* PTsl)
{
  __shared__ char sm[32768] __attribute__((aligned(16)));
  prep_fast(M, n, 0, blockIdx.x, Gh, Gl, Th, Tl, PTsh, PTsl, sm, threadIdx.x);
}

// stepA: update col k+1 (all by) and row k+1 (bx != k+1). grid 2nb-1.
__global__ __launch_bounds__(256) void gj_stepA_kernel(
    const float* __restrict__ Min, float* __restrict__ Mout, int n, int k,
    const bf16_t* __restrict__ Gh, const bf16_t* __restrict__ Gl,
    const bf16_t* __restrict__ Th, const bf16_t* __restrict__ Tl)
{
  __shared__ char sm[32768] __attribute__((aligned(16)));
  const int nb = n >> 7;
  const int bid = blockIdx.x;
  int by, bx;
  if (bid < nb){ by = bid; bx = k+1; }
  else { by = k+1; bx = bid-nb; if (bx >= k+1) bx++; }
  update_tile(Min, Mout, n, k, by, bx, Gh, Gl, Th, Tl, sm, threadIdx.x);
}

// stepB: blocks [0,nb) = prep_fast(k+1) from Mout; rest = remaining updates.
__global__ __launch_bounds__(256) void gj_stepB_kernel(
    const float* __restrict__ Min, float* __restrict__ Mout, int n, int k,
    const bf16_t* __restrict__ Gh, const bf16_t* __restrict__ Gl,
    const bf16_t* __restrict__ Th, const bf16_t* __restrict__ Tl,
    bf16_t* Gnh, bf16_t* Gnl, bf16_t* Tnh, bf16_t* Tnl,
    bf16_t* PTsh, bf16_t* PTsl)
{
  __shared__ char sm[32768] __attribute__((aligned(16)));
  const int nb = n >> 7;
  const int bid = blockIdx.x, tid = threadIdx.x;
  if (bid < nb){
    prep_fast(Mout, n, k+1, bid, Gnh, Gnl, Tnh, Tnl, PTsh, PTsl, sm, tid);
  } else {
    int q = bid - nb;
    int by = q/(nb-1), bx = q - by*(nb-1);
    if (by >= k+1) by++;
    if (bx >= k+1) bx++;
    update_tile(Min, Mout, n, k, by, bx, Gh, Gl, Th, Tl, sm, tid);
  }
}

// last step: all nb*nb tiles, no prep. grid nb*nb.
__global__ __launch_bounds__(256) void gj_stepL_kernel(
    const float* __restrict__ Min, float* __restrict__ Mout, int n, int k,
    const bf16_t* __restrict__ Gh, const bf16_t* __restrict__ Gl,
    const bf16_t* __restrict__ Th, const bf16_t* __restrict__ Tl)
{
  __shared__ char sm[32768] __attribute__((aligned(16)));
  const int nb = n >> 7;
  int by = blockIdx.x / nb, bx = blockIdx.x - by*nb;
  update_tile(Min, Mout, n, k, by, bx, Gh, Gl, Th, Tl, sm, threadIdx.x);
}

// ---------------------------------------------------------------------------
// Split-K Gram partials: Gp[z][i][j] = sum_{kappa in slice z} V[kappa][i]*V[kappa][j]
// ---------------------------------------------------------------------------
template<int TRANS>
__global__ __launch_bounds__(256) void gram_partial_kernel(
    const float* __restrict__ V, int ldv, int n, int Ks,
    float* __restrict__ Gp)
{
  __shared__ float Vi[16][132];
  __shared__ float Vj[16][132];
  const int cj = blockIdx.x, ci = blockIdx.y, z = blockIdx.z;
  const int tid = threadIdx.x;
  const int i0 = ci<<7, j0 = cj<<7;
  const int tx = tid&15, ty = tid>>4;
  float acc[8][8] = {};
  for (int k0 = z*Ks; k0 < (z+1)*Ks; k0 += 16){
    if (TRANS == 0){
      for (int q=tid; q<512; q+=256){
        int kr = q>>5, c4 = (q&31)<<2;
        *(float4*)&Vi[kr][c4] = *(const float4*)&V[(size_t)(k0+kr)*ldv + i0 + c4];
        *(float4*)&Vj[kr][c4] = *(const float4*)&V[(size_t)(k0+kr)*ldv + j0 + c4];
      }
    } else {
      for (int q=tid; q<512; q+=256){
        int c = q>>2, qq = (q&3)<<2;
        float4 a = *(const float4*)&V[(size_t)(i0+c)*ldv + k0 + qq];
        Vi[qq+0][c]=a.x; Vi[qq+1][c]=a.y; Vi[qq+2][c]=a.z; Vi[qq+3][c]=a.w;
        float4 b = *(const float4*)&V[(size_t)(j0+c)*ldv + k0 + qq];
        Vj[qq+0][c]=b.x; Vj[qq+1][c]=b.y; Vj[qq+2][c]=b.z; Vj[qq+3][c]=b.w;
      }
    }
    __syncthreads();
#pragma unroll
    for (int kr=0; kr<16; kr++){
      float a[8], b[8];
      *(float4*)&a[0] = *(const float4*)&Vi[kr][(ty<<3)];
      *(float4*)&a[4] = *(const float4*)&Vi[kr][(ty<<3)+4];
      *(float4*)&b[0] = *(const float4*)&Vj[kr][(tx<<3)];
      *(float4*)&b[4] = *(const float4*)&Vj[kr][(tx<<3)+4];
#pragma unroll
      for (int i=0;i<8;i++)
#pragma unroll
        for (int jj=0;jj<8;jj++) acc[i][jj] = fmaf(a[i], b[jj], acc[i][jj]);
    }
    __syncthreads();
  }
#pragma unroll
  for (int i=0;i<8;i++)
#pragma unroll
    for (int jj=0;jj<8;jj++)
      Gp[(size_t)z*n*n + (size_t)(i0+(ty<<3)+i)*n + j0+(tx<<3)+jj] = acc[i][jj];
}

// ---------------------------------------------------------------------------
// small kernels
// ---------------------------------------------------------------------------
__global__ void sumsq_kernel(const float* __restrict__ w, int n, float* __restrict__ acc){
  float s = 0.0f;
  for (int i = blockIdx.x*blockDim.x + threadIdx.x; i < n; i += gridDim.x*blockDim.x){
    float v = w[i]; s = fmaf(v, v, s);
  }
#pragma unroll
  for (int o=32;o;o>>=1) s += __shfl_xor(s, o);
  if ((threadIdx.x & 63) == 0) atomicAdd(acc, s);
}

__global__ void scales_kernel(float* scal, const float* a0, const float* a1,
                              const float* a2, const float* a3){
  if (threadIdx.x==0 && blockIdx.x==0){
    float s;
    s = a0[0]/sqrtf(scal[0]); scal[4]=s; scal[8]=s*s;
    s = a1[0]/sqrtf(scal[1]); scal[5]=s; scal[9]=s*s;
    s = a2[0]/sqrtf(scal[2]); scal[6]=s; scal[10]=s*s;
    s = a3[0]/sqrtf(scal[3]); scal[7]=s; scal[11]=s*s;
  }
}

__global__ void build_mm_kernel(const float* __restrict__ W, const float* __restrict__ scal,
                                float* __restrict__ Mo){
  int j = (blockIdx.x<<4) + (threadIdx.x&15);
  int i = (blockIdx.y<<4) + (threadIdx.x>>4);
  float s = scal[5];
  float a = s*(W[((size_t)i<<12)+j] - W[((size_t)j<<12)+i]);
  Mo[((size_t)i<<12)+j] = ((i==j)?1.0f:0.0f) + a;
}

// Mo = I + s*(W - W^T) + s2 * sum_s Gp[s]
__global__ void build_rect_kernel(const float* __restrict__ W, int ldw, int transw, int n,
      const float* __restrict__ Gp, int S,
      const float* __restrict__ scal, int sidx, int sidx2,
      float* __restrict__ Mo){
  int j = (blockIdx.x<<4)+(threadIdx.x&15);
  int i = (blockIdx.y<<4)+(threadIdx.x>>4);
  float s = scal[sidx], s2 = scal[sidx2];
  float wij = transw ? W[(size_t)j*ldw+i] : W[(size_t)i*ldw+j];
  float wji = transw ? W[(size_t)i*ldw+j] : W[(size_t)j*ldw+i];
  float g = 0.0f;
  for (int ss=0; ss<S; ss++) g += Gp[(size_t)ss*n*n + (size_t)i*n + j];
  Mo[(size_t)i*n + j] = ((i==j)?1.0f:0.0f) + s*(wij - wji) + s2*g;
}

// dst = 2*X - I
template<typename TD>
__global__ void qtop_kernel(const float* __restrict__ X, int n,
                            TD* __restrict__ dst, int ldd){
  int j = blockIdx.x*blockDim.x + threadIdx.x;
  int i = blockIdx.y;
  if (j<n) storeS(&dst[(size_t)i*ldd+j],
                  2.0f*X[(size_t)i*n+j] - ((i==j)?1.0f:0.0f));
}

// fp32 tiled transpose: dst[c][r] = src[r][c]; rows,cols % 32 == 0
__global__ void transposeF_kernel(const float* __restrict__ src, int ls,
                                  float* __restrict__ dst, int ld){
  __shared__ float t[32][33];
  int c0 = blockIdx.x<<5, r0 = blockIdx.y<<5;
  int tx = threadIdx.x & 31, ty = threadIdx.x >> 5;
#pragma unroll
  for (int i=0;i<4;i++) t[ty+i*8][tx] = src[(size_t)(r0+ty+i*8)*ls + c0+tx];
  __syncthreads();
#pragma unroll
  for (int i=0;i<4;i++) dst[(size_t)(c0+ty+i*8)*ld + r0+tx] = t[tx][ty+i*8];
}

// A' = [ bf16(h) | bf16(x) | bf16(x - bf16(x)) ]  (8192 x 2176)
__global__ void pack_A_kernel(const float* __restrict__ h, const float* __restrict__ x,
                              bf16_t* __restrict__ Ap){
  int c = blockIdx.x*blockDim.x + threadIdx.x;
  int m = blockIdx.y;
  if (c >= 2176) return;
  float v;
  if (c < 128)       v = h[(size_t)m*128 + c];
  else if (c < 1152) v = x[(size_t)m*1024 + (c-128)];
  else {
    float xv = x[(size_t)m*1024 + (c-1152)];
    v = xv - bf2f(f2bf(xv));
  }
  Ap[(size_t)m*2176 + c] = f2bf(v);
}

__global__ void dup_kernel(bf16_t* __restrict__ Bp){
  int c = blockIdx.x*blockDim.x + threadIdx.x;   // 0..1023
  int r = blockIdx.y;
  Bp[(size_t)r*2176 + 1152 + c] = Bp[(size_t)r*2176 + 128 + c];
}

__global__ void addvec_kernel(const float* __restrict__ a, const float* __restrict__ b,
                              float* __restrict__ c, int n){
  int i = blockIdx.x*blockDim.x + threadIdx.x;
  if (i<n) c[i] = a[i] + b[i];
}

// simplex-with-floor projection: one wave per row of 128; 30 Newton iters.
__global__ __launch_bounds__(256) void project_kernel(
    const float* __restrict__ ft, const float* __restrict__ h, float* __restrict__ out){
  int row  = (blockIdx.x<<2) + (threadIdx.x>>6);
  int lane = threadIdx.x & 63;
  const float* fr = ft + ((size_t)row<<7);
  const float* hr = h  + ((size_t)row<<7);
  float f0 = fr[lane], f1 = fr[lane+64];
  float l0 = -ALPHA_1*(expf(SIGMA_1*hr[lane])   - 1.0f);
  float l1 = -ALPHA_1*(expf(SIGMA_1*hr[lane+64])- 1.0f);
  float s = f0 + f1;
#pragma unroll
  for (int o=32;o;o>>=1) s += __shfl_xor(s, o);
  float lam = s * (1.0f/128.0f);
  for (int it=0; it<30; it++){
    float a0 = f0 - lam, a1 = f1 - lam;
    float g = fmaxf(a0,l0) + fmaxf(a1,l1);
    float c = (a0>l0 ? 1.0f:0.0f) + (a1>l1 ? 1.0f:0.0f);
#pragma unroll
    for (int o=32;o;o>>=1){ g += __shfl_xor(g,o); c += __shfl_xor(c,o); }
    lam += g / fmaxf(c, 1.0f);
  }
  out[((size_t)row<<7)+lane]    = fmaxf(f0-lam, l0);
  out[((size_t)row<<7)+lane+64] = fmaxf(f1-lam, l1);
}

// ---------------------------------------------------------------------------
// host-side helpers (enqueue only)
// ---------------------------------------------------------------------------
template<typename TC, int RELU>
static inline void mfma_nt(hipStream_t st, int Mm, int Nn, int Kk,
    const bf16_t* A, int lda, const bf16_t* B, int ldb, TC* C, int ldc,
    const float* bias){
  dim3 grid(Nn>>7, Mm>>7);
  mfma_nt_kernel<TC,RELU><<<grid, 256, 0, st>>>(Mm,Nn,Kk,A,lda,B,ldb,C,ldc,bias);
}

template<typename TC>
static inline void fgemm(hipStream_t st, int Mm, int Nn, int Kk,
    const float* A, int lda, const float* Bt, int ldb, TC* C, int ldc,
    float alpha, const float* aptr, float beta){
  dim3 grid(Nn>>7, Mm>>7);
  fgemm_nt_kernel<TC><<<grid, 256, 0, st>>>(Mm,Nn,Kk,A,lda,Bt,ldb,C,ldc,
                                            alpha,aptr,beta, 1<<30);
}

// Ping-pong block Gauss-Jordan inverse; nb even -> result lands back in M.
// prep0; per step {stepA; stepB(with overlapped prep(k+1))}; last step stepL.
static void gj_inverse3(hipStream_t st, float* M, float* Mtmp, int n,
    bf16_t* Gh, bf16_t* Gl, bf16_t* Th, bf16_t* Tl,
    bf16_t* PTsh, bf16_t* PTsl){
  const int nb = n >> 7;
  const size_t gstep = (size_t)nb << 14;
  gj_prep0_kernel<<<nb, 256, 0, st>>>(M, n, Gh, Gl, Th, Tl, PTsh, PTsl);
  for (int k=0; k<nb; k++){
    const float* Min = (k&1) ? Mtmp : M;
    float* Mout      = (k&1) ? M : Mtmp;
    const size_t pc = (size_t)(k&1)*gstep, pn = (size_t)((k&1)^1)*gstep;
    if (k < nb-1){
      gj_stepA_kernel<<<2*nb-1, 256, 0, st>>>(Min, Mout, n, k,
          Gh+pc, Gl+pc, Th+pc, Tl+pc);
      gj_stepB_kernel<<<nb + (nb-1)*(nb-1), 256, 0, st>>>(Min, Mout, n, k,
          Gh+pc, Gl+pc, Th+pc, Tl+pc,
          Gh+pn, Gl+pn, Th+pn, Tl+pn, PTsh, PTsl);
    } else {
      gj_stepL_kernel<<<nb*nb, 256, 0, st>>>(Min, Mout, n, k,
          Gh+pc, Gl+pc, Th+pc, Tl+pc);
    }
  }
}

extern "C" void kernel_launch(void* const* d_in, const int* in_sizes, int n_in,
                              void* d_out, int out_size, void* d_ws, size_t ws_size,
                              hipStream_t stream){
  (void)in_sizes; (void)n_in; (void)out_size; (void)ws_size;
  const float* h    = (const float*)d_in[0];   // 8192x128
  const float* x    = (const float*)d_in[1];   // 8192x1024
  const float* Whm  = (const float*)d_in[2];   // 4096x128
  const float* bhm  = (const float*)d_in[3];
  const float* ahm  = (const float*)d_in[4];
  const float* Wmm  = (const float*)d_in[5];   // 4096x4096
  const float* bmm  = (const float*)d_in[6];
  const float* amm  = (const float*)d_in[7];
  const float* Wmh  = (const float*)d_in[8];   // 128x4096
  const float* bmh  = (const float*)d_in[9];
  const float* amh  = (const float*)d_in[10];
  const float* Wux  = (const float*)d_in[11];  // 4096x1024
  const float* bux  = (const float*)d_in[12];
  const float* auxs = (const float*)d_in[13];
  float* out = (float*)d_out;

  // ---- workspace (~188 MiB peak; 189 MiB proven safe) ----
  char* wp = (char*)d_ws;
  auto alloc = [&](size_t bytes)->void*{
    void* p = (void*)wp; wp += (bytes + 255) & ~(size_t)255; return p; };
  float*  scal   = (float*)alloc(4096);
  float*  Mhm    = (float*)alloc((size_t)128*128*4);
  float*  Mmh    = (float*)alloc((size_t)128*128*4);
  float*  P128   = (float*)alloc((size_t)128*128*4);
  float*  PT128  = (float*)alloc((size_t)128*128*4);
  bf16_t* GhB    = (bf16_t*)alloc((size_t)2*32*16384*2);  // 2 MiB (2 parities)
  bf16_t* GlB    = (bf16_t*)alloc((size_t)2*32*16384*2);  // 2 MiB
  bf16_t* ThB    = (bf16_t*)alloc((size_t)2*32*16384*2);  // 2 MiB
  bf16_t* TlB    = (bf16_t*)alloc((size_t)2*32*16384*2);  // 2 MiB
  bf16_t* PTsh   = (bf16_t*)alloc((size_t)32*16384*2);    // 1 MiB (per-block PT)
  bf16_t* PTsl   = (bf16_t*)alloc((size_t)32*16384*2);    // 1 MiB
  bf16_t* Qmh_b  = (bf16_t*)alloc((size_t)128*4096*2);    // 1 MiB
  float*  bsum   = (float*)alloc((size_t)4096*4);
  bf16_t* Bp     = (bf16_t*)alloc((size_t)4096*2176*2);   // 17 MiB [Qhm|Qux|Qux_dup]
  float*  R1     = (float*)alloc((size_t)4096*4096*4);    // 64 MiB
  float*  R2     = (float*)alloc((size_t)4096*4096*4);    // 64 MiB
  bf16_t* Qmmb   = (bf16_t*)alloc((size_t)4096*4096*2);   // 32 MiB
  // lifetime aliases:
  float*  gram23 = R1;                          // phases 2/3: 31 Gram partials (~2 MiB)
  float*  WmhTv  = R1 + (size_t)1024*1024;      // phase 3: 3968x128 (disjoint, +4 MiB)
  float*  Mmm  = R1;                            // I+A_mm -> inverse (GJ ping-pong R1<->R2)
  bf16_t* Ap   = (bf16_t*)R1;                   // packed A' (after qtop)
  bf16_t* z2   = (bf16_t*)R1;                   // GEMM2 out
  float*  Mux  = R2 + (size_t)1024*1024;        // phase-1 carve of R2
  float*  XuxT = R2 + (size_t)5*1024*1024;      //   4 MiB
  float*  Gp1  = R2 + (size_t)6*1024*1024;      //   16 MiB (4 split-K Gram partials)
  bf16_t* z    = (bf16_t*)R2;                   // GEMM1 out
  float*  ftl  = R2;                            // GEMM3 out (z dead)

  // ---- phase 0: scales s = a/||W||_F
  hipMemsetAsync(scal, 0, 16*sizeof(float), stream);
  sumsq_kernel<<<512,256,0,stream>>>(Whm, 4096*128,  scal+0);
  sumsq_kernel<<<512,256,0,stream>>>(Wmm, 4096*4096, scal+1);
  sumsq_kernel<<<512,256,0,stream>>>(Wmh, 128*4096,  scal+2);
  sumsq_kernel<<<512,256,0,stream>>>(Wux, 4096*1024, scal+3);
  scales_kernel<<<1,1,0,stream>>>(scal, ahm, amm, amh, auxs);

  // ---- phase 1: ux (1024) -> Bp cols [128,1152)
  gram_partial_kernel<0><<<dim3(8,8,4),256,0,stream>>>(
      Wux + (size_t)1024*1024, 1024, 1024, 768, Gp1);     // V = Wux[1024:]
  build_rect_kernel<<<dim3(64,64),256,0,stream>>>(Wux,1024,0,1024, Gp1,4, scal,7,11, Mux);
  gj_inverse3(stream, Mux, R1, 1024, GhB, GlB, ThB, TlB, PTsh, PTsl);
  transposeF_kernel<<<dim3(32,32),256,0,stream>>>(Mux, 1024, XuxT, 1024);
  qtop_kernel<bf16_t><<<dim3(4,1024),256,0,stream>>>(Mux, 1024, Bp+128, 2176);
  fgemm<bf16_t>(stream, 3072,1024,1024, Wux+(size_t)1024*1024,1024, XuxT,1024,
                Bp+(size_t)1024*2176+128, 2176, -2.0f,&scal[7], 0.0f);

  // ---- phase 2: hm (128) -> Bp cols [0,128)
  gram_partial_kernel<0><<<dim3(1,1,31),256,0,stream>>>(
      Whm + (size_t)128*128, 128, 128, 128, gram23);      // V = Whm[128:]
  build_rect_kernel<<<dim3(8,8),256,0,stream>>>(Whm,128,0,128, gram23,31, scal,4,8, Mhm);
  invert128_kernel<<<1,1024,0,stream>>>(Mhm,128,P128,PT128);
  qtop_kernel<bf16_t><<<dim3(1,128),256,0,stream>>>(P128, 128, Bp, 2176);
  fgemm<bf16_t>(stream, 3968,128,128, Whm+128*128,128, PT128,128,
                Bp+(size_t)128*2176, 2176, -2.0f,&scal[4], 0.0f);

  // ---- phase 3: mh (via W_mh^T) -> Qmh_b (128x4096)
  gram_partial_kernel<1><<<dim3(1,1,31),256,0,stream>>>(
      Wmh + 128, 4096, 128, 128, gram23);                 // V[kap][i]=Wmh[i][128+kap]
  build_rect_kernel<<<dim3(8,8),256,0,stream>>>(Wmh,4096,1,128, gram23,31, scal,6,10, Mmh);
  invert128_kernel<<<1,1024,0,stream>>>(Mmh,128,P128,PT128);
  qtop_kernel<bf16_t><<<dim3(1,128),256,0,stream>>>(PT128, 128, Qmh_b, 4096);
  transposeF_kernel<<<dim3(124,4),256,0,stream>>>(Wmh+128, 4096, WmhTv, 128);
  fgemm<bf16_t>(stream, 128,3968,128, PT128,128, WmhTv,128,
                Qmh_b+128, 4096, -2.0f,&scal[6], 0.0f);

  // ---- phase 4: mm (4096): GJ inverse ping-pong R1<->R2, then Q = 2X - I
  build_mm_kernel<<<dim3(256,256),256,0,stream>>>(Wmm, scal, Mmm);
  gj_inverse3(stream, Mmm, R2, 4096, GhB, GlB, ThB, TlB, PTsh, PTsl);
  qtop_kernel<bf16_t><<<dim3(16,4096),256,0,stream>>>(Mmm, 4096, Qmmb, 4096);
  // R1 now dead -> Ap; R2 free -> z.

  // ---- phase 5: pack A', finish B', bias sum
  pack_A_kernel<<<dim3(9,8192),256,0,stream>>>(h, x, Ap);
  dup_kernel<<<dim3(4,4096),256,0,stream>>>(Bp);
  addvec_kernel<<<16,256,0,stream>>>(bhm, bux, bsum, 4096);

  // ---- phases 6-8: forward (bf16 MFMA)
  mfma_nt<bf16_t,1>(stream, 8192,4096,2176, Ap,2176, Bp,2176, z,4096, bsum);
  mfma_nt<bf16_t,1>(stream, 8192,4096,4096, z,4096, Qmmb,4096, z2,4096, bmm);
  mfma_nt<float,0>(stream, 8192, 128,4096, z2,4096, Qmh_b,4096, ftl,128, bmh);

  // ---- phase 9: projection
  project_kernel<<<2048,256,0,stream>>>(ftl, h, out);
}

// Round 8
// 6346.938 us; speedup vs baseline: 4.1014x; 4.1014x over previous
//
#include <hip/hip_runtime.h>
#include <math.h>

// Problem: B=8192, NH=128, M=4096, XD=1024
#define ALPHA_1 100.0f
#define SIGMA_1 0.02f

typedef unsigned short bf16_t;   // raw bf16 storage
typedef short  bf16x8  __attribute__((ext_vector_type(8)));   // MFMA A/B frag
typedef float  floatx4 __attribute__((ext_vector_type(4)));   // MFMA C/D frag

typedef __attribute__((address_space(1))) void glb_void;
typedef __attribute__((address_space(3))) void lds_void;

__device__ __forceinline__ float bf2f(bf16_t u){ return __uint_as_float(((unsigned)u)<<16); }
__device__ __forceinline__ bf16_t f2bf(float f){
  unsigned u = __float_as_uint(f);
  u += 0x7FFFu + ((u>>16)&1u);          // RNE
  return (bf16_t)(u>>16);
}

// split float4 -> bf16 hi + bf16 residual lo
__device__ __forceinline__ void split4(float4 v, ushort4& h, ushort4& l){
  h.x=f2bf(v.x); h.y=f2bf(v.y); h.z=f2bf(v.z); h.w=f2bf(v.w);
  l.x=f2bf(v.x-bf2f(h.x)); l.y=f2bf(v.y-bf2f(h.y));
  l.z=f2bf(v.z-bf2f(h.z)); l.w=f2bf(v.w-bf2f(h.w));
}

__device__ __forceinline__ float4 load4f(const float* p){ return *(const float4*)p; }
__device__ __forceinline__ float loadS(const float* p){ return *p; }
__device__ __forceinline__ float loadS(const bf16_t* p){ return bf2f(*p); }
__device__ __forceinline__ void storeS(float* p, float v){ *p = v; }
__device__ __forceinline__ void storeS(bf16_t* p, float v){ *p = f2bf(v); }

// async 16B global->LDS (gfx950). LDS side is wave-uniform base + lane*16.
__device__ __forceinline__ void async_copy16(void* lds, const void* g){
  __builtin_amdgcn_global_load_lds((glb_void*)g, (lds_void*)lds, 16, 0, 0);
}

// ---------------------------------------------------------------------------
// bf16 MFMA NT GEMM (forward path): C[M][N] = sum_k A[m][k]*B[n][k] + bias.
// 128x128 tile, BK=64, 4 waves of 64x64. NO XCD swizzle: operands are
// L3-resident and chunked swizzle doubled FETCH_SIZE (round-5 measurement).
// ---------------------------------------------------------------------------
template<typename TC, int RELU>
__global__ __launch_bounds__(256) void mfma_nt_kernel(
    int Mm, int Nn, int Kk,
    const bf16_t* __restrict__ A, int lda,
    const bf16_t* __restrict__ B, int ldb,
    TC* __restrict__ C, int ldc,
    const float* __restrict__ bias)
{
  __shared__ bf16_t As[128*64];
  __shared__ bf16_t Bs[128*64];
  const int tid  = threadIdx.x;
  const int lane = tid & 63, wv = tid >> 6;
  const int m0 = (int)(blockIdx.y << 7), n0 = (int)(blockIdx.x << 7);
  const int wm = (wv >> 1) << 6, wn = (wv & 1) << 6;
  const int rbase = wv << 5;                 // 32 rows per wave

  floatx4 acc[4][4] = {};

  for (int kk = 0; kk < Kk; kk += 64){
    __syncthreads();                         // prev iter's readers done
#pragma unroll
    for (int q=0;q<4;q++){
      int row = rbase + (q<<3) + (lane>>3);
      int cg  = (lane&7) ^ (row&7);          // swizzled global chunk
      async_copy16(&As[(size_t)(rbase+(q<<3))<<6],
                   A + (size_t)(m0+row)*lda + kk + (cg<<3));
      async_copy16(&Bs[(size_t)(rbase+(q<<3))<<6],
                   B + (size_t)(n0+row)*ldb + kk + (cg<<3));
    }
    __syncthreads();
#pragma unroll
    for (int ks=0; ks<2; ks++){
      bf16x8 af[4], bf[4];
      int quad = lane>>4, mr = lane&15;
      int c = quad + (ks<<2);                // chunk 0..7
#pragma unroll
      for (int i=0;i<4;i++){
        int rowa = wm + i*16 + mr;
        af[i] = *(const bf16x8*)&As[(rowa<<6) + ((c ^ (rowa&7))<<3)];
        int rowb = wn + i*16 + mr;
        bf[i] = *(const bf16x8*)&Bs[(rowb<<6) + ((c ^ (rowb&7))<<3)];
      }
#pragma unroll
      for (int i=0;i<4;i++)
#pragma unroll
        for (int j=0;j<4;j++)
          acc[i][j] = __builtin_amdgcn_mfma_f32_16x16x32_bf16(af[i], bf[j], acc[i][j], 0,0,0);
    }
  }
#pragma unroll
  for (int i=0;i<4;i++){
#pragma unroll
    for (int j=0;j<4;j++){
      int rbase2 = m0 + wm + i*16 + (lane>>4)*4;
      int col    = n0 + wn + j*16 + (lane&15);
      float bv = bias ? bias[col] : 0.0f;
#pragma unroll
      for (int r=0;r<4;r++){
        float v = acc[i][j][r] + bv;
        if (RELU) v = fmaxf(v, 0.0f);
        storeS(&C[(size_t)(rbase2+r)*ldc + col], v);
      }
    }
  }
}

// ---------------------------------------------------------------------------
// fp32-precision NT GEMM on matrix cores via bf16 hi/lo split (bf16x3):
// C[M][N] = alpha*(aptr?)*sum_k A[m][k]*Bt[n][k] + beta*C. 128x128 tile, BK=64.
// ---------------------------------------------------------------------------
template<typename TC>
__global__ __launch_bounds__(256) void fgemm_nt_kernel(
    int Mm, int Nn, int Kk,
    const float* __restrict__ A, int lda,
    const float* __restrict__ Bt, int ldb,
    TC* __restrict__ C, int ldc,
    float alpha, const float* __restrict__ alpha_ptr, float beta, int skipk)
{
  __shared__ bf16_t Ah[128*64], Al[128*64], Bh[128*64], Bl[128*64];
  const int tid = threadIdx.x;
  const int lane = tid & 63, wv = tid >> 6;
  int by = blockIdx.y; if (by >= skipk) by++;
  const int m0 = by << 7, n0 = blockIdx.x << 7;
  const int wm = (wv >> 1) << 6, wn = (wv & 1) << 6;
  floatx4 acc[4][4] = {};

  for (int kk = 0; kk < Kk; kk += 64){
    float4 va[8], vb[8];
#pragma unroll
    for (int i=0;i<8;i++){
      int idx = (tid<<3) + i;               // 0..2047
      int row = idx >> 4;                   // 0..127
      int cg  = idx & 15;                   // float4 granule
      va[i] = load4f(A  + (size_t)(m0+row)*lda + kk + (cg<<2));
      vb[i] = load4f(Bt + (size_t)(n0+row)*ldb + kk + (cg<<2));
    }
    __syncthreads();
#pragma unroll
    for (int i=0;i<8;i++){
      int idx = (tid<<3) + i;
      int row = idx >> 4, cg = idx & 15;
      int off = (row<<6) + (((cg>>1) ^ (row&7))<<3) + ((cg&1)<<2);
      ushort4 hv, lv; split4(va[i], hv, lv);
      *(ushort4*)&Ah[off] = hv; *(ushort4*)&Al[off] = lv;
      ushort4 hw, lw; split4(vb[i], hw, lw);
      *(ushort4*)&Bh[off] = hw; *(ushort4*)&Bl[off] = lw;
    }
    __syncthreads();
#pragma unroll
    for (int ks=0; ks<2; ks++){
      int quad = lane>>4, mr = lane&15;
      int c = quad + (ks<<2);
      bf16x8 ah[4], al[4], bh[4], bl[4];
#pragma unroll
      for (int i=0;i<4;i++){
        int rowa = wm + i*16 + mr; int sa = (rowa<<6) + ((c ^ (rowa&7))<<3);
        ah[i] = *(const bf16x8*)&Ah[sa]; al[i] = *(const bf16x8*)&Al[sa];
        int rowb = wn + i*16 + mr; int sb = (rowb<<6) + ((c ^ (rowb&7))<<3);
        bh[i] = *(const bf16x8*)&Bh[sb]; bl[i] = *(const bf16x8*)&Bl[sb];
      }
#pragma unroll
      for (int i=0;i<4;i++)
#pragma unroll
        for (int j=0;j<4;j++){
          acc[i][j] = __builtin_amdgcn_mfma_f32_16x16x32_bf16(ah[i], bl[j], acc[i][j], 0,0,0);
          acc[i][j] = __builtin_amdgcn_mfma_f32_16x16x32_bf16(al[i], bh[j], acc[i][j], 0,0,0);
          acc[i][j] = __builtin_amdgcn_mfma_f32_16x16x32_bf16(ah[i], bh[j], acc[i][j], 0,0,0);
        }
    }
    __syncthreads();
  }
  float am = alpha;
  if (alpha_ptr) am *= *alpha_ptr;
#pragma unroll
  for (int i=0;i<4;i++){
#pragma unroll
    for (int j=0;j<4;j++){
      int rb = m0 + wm + i*16 + (lane>>4)*4;
      int col = n0 + wn + j*16 + (lane&15);
#pragma unroll
      for (int r=0;r<4;r++){
        size_t off = (size_t)(rb+r)*ldc + col;
        float v = am * acc[i][j][r];
        if (beta != 0.0f) v = fmaf(beta, loadS(&C[off]), v);
        storeS(&C[off], v);
      }
    }
  }
}

// ---------------------------------------------------------------------------
// 128x128 Gauss-Jordan inverse (no pivot), 1024 threads, register-resident.
// Writes inverse AND its transpose. (Used standalone by phases 2/3.)
// ---------------------------------------------------------------------------
__global__ __launch_bounds__(1024) void invert128_kernel(
    const float* __restrict__ src, int ld,
    float* __restrict__ dst, float* __restrict__ dstT)
{
  __shared__ float brow[2][8*36];            // [parity][sub*36 + col]
  const int t = threadIdx.x;
  const int r = t>>3, sub = t&7;
  const int lane = t & 63;
  const int cb = (sub&3)<<5;
  const bool isA = sub < 4;
  float own[32];
  if (isA){
#pragma unroll
    for (int i=0;i<32;i++) own[i] = src[(size_t)r*ld + cb + i];
  } else {
#pragma unroll
    for (int i=0;i<32;i++) own[i] = (cb+i == r) ? 1.0f : 0.0f;
  }
  for (int pb=0; pb<4; pb++){
#pragma unroll
    for (int pi=0; pi<32; pi++){
      const int p = (pb<<5) + pi;
      float f = __shfl(own[pi], (lane & 56) | pb);
      float* bw = brow[p & 1];
      if (r == p){
        float ip = 1.0f / f;
#pragma unroll
        for (int i=0;i<32;i++) own[i] *= ip;
#pragma unroll
        for (int i=0;i<8;i++){
          float4 v;
          v.x = own[(i<<2)+0]; v.y = own[(i<<2)+1];
          v.z = own[(i<<2)+2]; v.w = own[(i<<2)+3];
          *(float4*)&bw[sub*36 + (i<<2)] = v;
        }
      }
      __syncthreads();
      if (r != p){
#pragma unroll
        for (int i=0;i<8;i++){
          float4 b = *(const float4*)&bw[sub*36 + (i<<2)];
          own[(i<<2)+0] = fmaf(-f, b.x, own[(i<<2)+0]);
          own[(i<<2)+1] = fmaf(-f, b.y, own[(i<<2)+1]);
          own[(i<<2)+2] = fmaf(-f, b.z, own[(i<<2)+2]);
          own[(i<<2)+3] = fmaf(-f, b.w, own[(i<<2)+3]);
        }
      }
    }
  }
  if (!isA){
#pragma unroll
    for (int i=0;i<32;i++){
      dst [(size_t)r*128 + cb + i] = own[i];
      dstT[(size_t)(cb+i)*128 + r] = own[i];
    }
  }
}

// ===========================================================================
// Block Gauss-Jordan inverse (round-5 proven machinery).
// Per step k (2 dispatches, ping-pong Min -> Mout):
//   gj_prepL (nb blocks x 1024 thr): every block redundantly inverts the
//     pivot tile (register GJ + shfl, P published to LDS). Then block ib:
//       T[ib] = M[k][ib]^T   (bf16 hi/lo, coalesced ushort4 stores)
//       G[ib] = -M[ib][k]*P  (fp32 FMA, stored bf16 hi/lo)
//     Block k stores G[k] = P and exits. No global PT, no races.
//   gj_update (nb x nb): Mout = (bx==k) ? G[by] : (by!=k)*Min + G[by]*T[bx]^T
//     via bf16x3 MFMA with PURE-COPY staging (split already done in prep).
// ===========================================================================
__global__ __launch_bounds__(1024) void gj_prepL_kernel(
    const float* __restrict__ Mc, int n, int k,
    bf16_t* __restrict__ Gh, bf16_t* __restrict__ Gl,
    bf16_t* __restrict__ Th, bf16_t* __restrict__ Tl)
{
  __shared__ float brow[2][8*36];
  __shared__ float Pl[128*132];
  __shared__ float Ast[128*132];
  const int t = threadIdx.x;
  const int ib = blockIdx.x;
  const int r = t>>3, sub = t&7;
  const int lane = t & 63;
  const int cb = (sub&3)<<5;
  const bool isA = sub < 4;
  const float* D = Mc + ((size_t)(k<<7))*n + (k<<7);
  float own[32];
  if (isA){
#pragma unroll
    for (int q=0;q<32;q++) own[q] = D[(size_t)r*n + cb + q];
  } else {
#pragma unroll
    for (int q=0;q<32;q++) own[q] = (cb+q == r) ? 1.0f : 0.0f;
  }
  for (int pb=0; pb<4; pb++){
#pragma unroll
    for (int pi=0; pi<32; pi++){
      const int p = (pb<<5) + pi;
      float f = __shfl(own[pi], (lane & 56) | pb);
      float* bw = brow[p & 1];
      if (r == p){
        float ip = 1.0f / f;
#pragma unroll
        for (int q=0;q<32;q++) own[q] *= ip;
#pragma unroll
        for (int q=0;q<8;q++){
          float4 v;
          v.x=own[(q<<2)+0]; v.y=own[(q<<2)+1]; v.z=own[(q<<2)+2]; v.w=own[(q<<2)+3];
          *(float4*)&bw[sub*36 + (q<<2)] = v;
        }
      }
      __syncthreads();
      if (r != p){
#pragma unroll
        for (int q=0;q<8;q++){
          float4 b = *(const float4*)&bw[sub*36 + (q<<2)];
          own[(q<<2)+0] = fmaf(-f, b.x, own[(q<<2)+0]);
          own[(q<<2)+1] = fmaf(-f, b.y, own[(q<<2)+1]);
          own[(q<<2)+2] = fmaf(-f, b.z, own[(q<<2)+2]);
          own[(q<<2)+3] = fmaf(-f, b.w, own[(q<<2)+3]);
        }
      }
    }
  }
  // publish P to LDS (and G[k] = P, hi/lo, if this is the pivot-row block)
  if (!isA){
#pragma unroll
    for (int q=0;q<8;q++){
      float4 v;
      v.x=own[(q<<2)+0]; v.y=own[(q<<2)+1]; v.z=own[(q<<2)+2]; v.w=own[(q<<2)+3];
      *(float4*)&Pl[r*132 + cb + (q<<2)] = v;
      if (ib == k){
        ushort4 hv, lv; split4(v, hv, lv);
        *(ushort4*)&Gh[((size_t)k<<14) + (r<<7) + cb + (q<<2)] = hv;
        *(ushort4*)&Gl[((size_t)k<<14) + (r<<7) + cb + (q<<2)] = lv;
      }
    }
  }
  __syncthreads();
  if (ib == k) return;

  // ---- T[ib] = transpose of tile (k, ib), via LDS staging, hi/lo stores
  const float* Ski = Mc + ((size_t)(k<<7))*n + (ib<<7);
#pragma unroll
  for (int q=0;q<4;q++){
    int f4 = (t<<2) + q;                 // 0..4095
    int rr = f4>>5, c4 = (f4&31)<<2;
    *(float4*)&Ast[rr*132 + c4] = *(const float4*)&Ski[(size_t)rr*n + c4];
  }
  __syncthreads();
#pragma unroll
  for (int q=0;q<4;q++){
    int f4 = (t<<2) + q;
    int cc = f4>>5, r4 = (f4&31)<<2;
    float4 v;
    v.x = Ast[(r4+0)*132 + cc]; v.y = Ast[(r4+1)*132 + cc];
    v.z = Ast[(r4+2)*132 + cc]; v.w = Ast[(r4+3)*132 + cc];
    ushort4 hv, lv; split4(v, hv, lv);
    *(ushort4*)&Th[((size_t)ib<<14) + (cc<<7) + r4] = hv;
    *(ushort4*)&Tl[((size_t)ib<<14) + (cc<<7) + r4] = lv;
  }
  __syncthreads();

  // ---- Ast = tile (ib, k)
  const float* Sik = Mc + ((size_t)(ib<<7))*n + (k<<7);
#pragma unroll
  for (int q=0;q<4;q++){
    int f4 = (t<<2) + q;
    int rr = f4>>5, c4 = (f4&31)<<2;
    *(float4*)&Ast[rr*132 + c4] = *(const float4*)&Sik[(size_t)rr*n + c4];
  }
  __syncthreads();

  // ---- G[ib] = -(Ast * P), fp32, 4x4 per thread, hi/lo stores
  const int tx = t&31, ty = t>>5;
  const int r0 = ty<<2, c0 = tx<<2;
  float acc[4][4] = {};
  for (int kq=0; kq<128; kq++){
    float4 b = *(const float4*)&Pl[kq*132 + c0];
    float a0 = Ast[(r0+0)*132 + kq];
    float a1 = Ast[(r0+1)*132 + kq];
    float a2 = Ast[(r0+2)*132 + kq];
    float a3 = Ast[(r0+3)*132 + kq];
    acc[0][0]=fmaf(a0,b.x,acc[0][0]); acc[0][1]=fmaf(a0,b.y,acc[0][1]);
    acc[0][2]=fmaf(a0,b.z,acc[0][2]); acc[0][3]=fmaf(a0,b.w,acc[0][3]);
    acc[1][0]=fmaf(a1,b.x,acc[1][0]); acc[1][1]=fmaf(a1,b.y,acc[1][1]);
    acc[1][2]=fmaf(a1,b.z,acc[1][2]); acc[1][3]=fmaf(a1,b.w,acc[1][3]);
    acc[2][0]=fmaf(a2,b.x,acc[2][0]); acc[2][1]=fmaf(a2,b.y,acc[2][1]);
    acc[2][2]=fmaf(a2,b.z,acc[2][2]); acc[2][3]=fmaf(a2,b.w,acc[2][3]);
    acc[3][0]=fmaf(a3,b.x,acc[3][0]); acc[3][1]=fmaf(a3,b.y,acc[3][1]);
    acc[3][2]=fmaf(a3,b.z,acc[3][2]); acc[3][3]=fmaf(a3,b.w,acc[3][3]);
  }
#pragma unroll
  for (int rr=0;rr<4;rr++){
    float4 v; v.x=-acc[rr][0]; v.y=-acc[rr][1]; v.z=-acc[rr][2]; v.w=-acc[rr][3];
    ushort4 hv, lv; split4(v, hv, lv);
    *(ushort4*)&Gh[((size_t)ib<<14) + ((size_t)(r0+rr)<<7) + c0] = hv;
    *(ushort4*)&Gl[((size_t)ib<<14) + ((size_t)(r0+rr)<<7) + c0] = lv;
  }
}

// gj_update: grid (nb, nb). Mout = (bx==k) ? G[by] : (by!=k)*Min + G[by]*T[bx]^T
__global__ __launch_bounds__(256) void gj_update_kernel(
    const float* __restrict__ Min, float* __restrict__ Mout, int n, int k,
    const bf16_t* __restrict__ Gh, const bf16_t* __restrict__ Gl,
    const bf16_t* __restrict__ Th, const bf16_t* __restrict__ Tl)
{
  const int bx = blockIdx.x, by = blockIdx.y;
  const int tid = threadIdx.x;
  if (bx == k){
    const bf16_t* sh = Gh + ((size_t)by<<14);
    const bf16_t* sl = Gl + ((size_t)by<<14);
    float* dst = Mout + ((size_t)(by<<7))*n + ((size_t)k<<7);
    for (int q=tid; q<4096; q+=256){
      int r=q>>5, c4=(q&31)<<2;
      ushort4 hv=*(const ushort4*)&sh[(r<<7)+c4];
      ushort4 lv=*(const ushort4*)&sl[(r<<7)+c4];
      float4 v; v.x=bf2f(hv.x)+bf2f(lv.x); v.y=bf2f(hv.y)+bf2f(lv.y);
                v.z=bf2f(hv.z)+bf2f(lv.z); v.w=bf2f(hv.w)+bf2f(lv.w);
      *(float4*)&dst[(size_t)r*n + c4] = v;
    }
    return;
  }
  __shared__ bf16_t Ah[128*64], Al[128*64], Bh[128*64], Bl[128*64];
  const int lane = tid & 63, wv = tid >> 6;
  const int wm = (wv >> 1) << 6, wn = (wv & 1) << 6;
  const bf16_t* gh = Gh + ((size_t)by<<14);
  const bf16_t* gl = Gl + ((size_t)by<<14);
  const bf16_t* th = Th + ((size_t)bx<<14);
  const bf16_t* tl = Tl + ((size_t)bx<<14);
  floatx4 acc[4][4] = {};

#pragma unroll
  for (int kk = 0; kk < 128; kk += 64){
    __syncthreads();
#pragma unroll
    for (int i=0;i<8;i++){
      int idx = (tid<<3) + i;               // 0..2047 ushort4 granules
      int row = idx >> 4, cg = idx & 15;
      int off = (row<<6) + (((cg>>1) ^ (row&7))<<3) + ((cg&1)<<2);
      *(ushort4*)&Ah[off] = *(const ushort4*)&gh[(row<<7) + kk + (cg<<2)];
      *(ushort4*)&Al[off] = *(const ushort4*)&gl[(row<<7) + kk + (cg<<2)];
      *(ushort4*)&Bh[off] = *(const ushort4*)&th[(row<<7) + kk + (cg<<2)];
      *(ushort4*)&Bl[off] = *(const ushort4*)&tl[(row<<7) + kk + (cg<<2)];
    }
    __syncthreads();
#pragma unroll
    for (int ks=0; ks<2; ks++){
      int quad = lane>>4, mr = lane&15;
      int c = quad + (ks<<2);
      bf16x8 ah[4], al[4], bh[4], bl[4];
#pragma unroll
      for (int i=0;i<4;i++){
        int rowa = wm + i*16 + mr; int sa = (rowa<<6) + ((c ^ (rowa&7))<<3);
        ah[i] = *(const bf16x8*)&Ah[sa]; al[i] = *(const bf16x8*)&Al[sa];
        int rowb = wn + i*16 + mr; int sb = (rowb<<6) + ((c ^ (rowb&7))<<3);
        bh[i] = *(const bf16x8*)&Bh[sb]; bl[i] = *(const bf16x8*)&Bl[sb];
      }
#pragma unroll
      for (int i=0;i<4;i++)
#pragma unroll
        for (int j=0;j<4;j++){
          acc[i][j] = __builtin_amdgcn_mfma_f32_16x16x32_bf16(ah[i], bl[j], acc[i][j], 0,0,0);
          acc[i][j] = __builtin_amdgcn_mfma_f32_16x16x32_bf16(al[i], bh[j], acc[i][j], 0,0,0);
          acc[i][j] = __builtin_amdgcn_mfma_f32_16x16x32_bf16(ah[i], bh[j], acc[i][j], 0,0,0);
        }
    }
  }
  const int addin = (by != k);
#pragma unroll
  for (int i=0;i<4;i++)
#pragma unroll
    for (int j=0;j<4;j++){
      int rb = (by<<7) + wm + i*16 + ((lane>>4)<<2);
      int col = (bx<<7) + wn + j*16 + (lane&15);
#pragma unroll
      for (int r4=0;r4<4;r4++){
        size_t off = (size_t)(rb+r4)*n + col;
        float v = acc[i][j][r4];
        if (addin) v += Min[off];
        Mout[off] = v;
      }
    }
}

// ---------------------------------------------------------------------------
// Split-K Gram partials: Gp[z][i][j] = sum_{kappa in slice z} V[kappa][i]*V[kappa][j]
// ---------------------------------------------------------------------------
template<int TRANS>
__global__ __launch_bounds__(256) void gram_partial_kernel(
    const float* __restrict__ V, int ldv, int n, int Ks,
    float* __restrict__ Gp)
{
  __shared__ float Vi[16][132];
  __shared__ float Vj[16][132];
  const int cj = blockIdx.x, ci = blockIdx.y, z = blockIdx.z;
  const int tid = threadIdx.x;
  const int i0 = ci<<7, j0 = cj<<7;
  const int tx = tid&15, ty = tid>>4;
  float acc[8][8] = {};
  for (int k0 = z*Ks; k0 < (z+1)*Ks; k0 += 16){
    if (TRANS == 0){
      for (int q=tid; q<512; q+=256){
        int kr = q>>5, c4 = (q&31)<<2;
        *(float4*)&Vi[kr][c4] = *(const float4*)&V[(size_t)(k0+kr)*ldv + i0 + c4];
        *(float4*)&Vj[kr][c4] = *(const float4*)&V[(size_t)(k0+kr)*ldv + j0 + c4];
      }
    } else {
      for (int q=tid; q<512; q+=256){
        int c = q>>2, qq = (q&3)<<2;
        float4 a = *(const float4*)&V[(size_t)(i0+c)*ldv + k0 + qq];
        Vi[qq+0][c]=a.x; Vi[qq+1][c]=a.y; Vi[qq+2][c]=a.z; Vi[qq+3][c]=a.w;
        float4 b = *(const float4*)&V[(size_t)(j0+c)*ldv + k0 + qq];
        Vj[qq+0][c]=b.x; Vj[qq+1][c]=b.y; Vj[qq+2][c]=b.z; Vj[qq+3][c]=b.w;
      }
    }
    __syncthreads();
#pragma unroll
    for (int kr=0; kr<16; kr++){
      float a[8], b[8];
      *(float4*)&a[0] = *(const float4*)&Vi[kr][(ty<<3)];
      *(float4*)&a[4] = *(const float4*)&Vi[kr][(ty<<3)+4];
      *(float4*)&b[0] = *(const float4*)&Vj[kr][(tx<<3)];
      *(float4*)&b[4] = *(const float4*)&Vj[kr][(tx<<3)+4];
#pragma unroll
      for (int i=0;i<8;i++)
#pragma unroll
        for (int jj=0;jj<8;jj++) acc[i][jj] = fmaf(a[i], b[jj], acc[i][jj]);
    }
    __syncthreads();
  }
#pragma unroll
  for (int i=0;i<8;i++)
#pragma unroll
    for (int jj=0;jj<8;jj++)
      Gp[(size_t)z*n*n + (size_t)(i0+(ty<<3)+i)*n + j0+(tx<<3)+jj] = acc[i][jj];
}

// ---------------------------------------------------------------------------
// small kernels
// ---------------------------------------------------------------------------
__global__ void sumsq_kernel(const float* __restrict__ w, int n, float* __restrict__ acc){
  float s = 0.0f;
  for (int i = blockIdx.x*blockDim.x + threadIdx.x; i < n; i += gridDim.x*blockDim.x){
    float v = w[i]; s = fmaf(v, v, s);
  }
#pragma unroll
  for (int o=32;o;o>>=1) s += __shfl_xor(s, o);
  if ((threadIdx.x & 63) == 0) atomicAdd(acc, s);
}

__global__ void scales_kernel(float* scal, const float* a0, const float* a1,
                              const float* a2, const float* a3){
  if (threadIdx.x==0 && blockIdx.x==0){
    float s;
    s = a0[0]/sqrtf(scal[0]); scal[4]=s; scal[8]=s*s;
    s = a1[0]/sqrtf(scal[1]); scal[5]=s; scal[9]=s*s;
    s = a2[0]/sqrtf(scal[2]); scal[6]=s; scal[10]=s*s;
    s = a3[0]/sqrtf(scal[3]); scal[7]=s; scal[11]=s*s;
  }
}

__global__ void build_mm_kernel(const float* __restrict__ W, const float* __restrict__ scal,
                                float* __restrict__ Mo){
  int j = (blockIdx.x<<4) + (threadIdx.x&15);
  int i = (blockIdx.y<<4) + (threadIdx.x>>4);
  float s = scal[5];
  float a = s*(W[((size_t)i<<12)+j] - W[((size_t)j<<12)+i]);
  Mo[((size_t)i<<12)+j] = ((i==j)?1.0f:0.0f) + a;
}

// Mo = I + s*(W - W^T) + s2 * sum_s Gp[s]
__global__ void build_rect_kernel(const float* __restrict__ W, int ldw, int transw, int n,
      const float* __restrict__ Gp, int S,
      const float* __restrict__ scal, int sidx, int sidx2,
      float* __restrict__ Mo){
  int j = (blockIdx.x<<4)+(threadIdx.x&15);
  int i = (blockIdx.y<<4)+(threadIdx.x>>4);
  float s = scal[sidx], s2 = scal[sidx2];
  float wij = transw ? W[(size_t)j*ldw+i] : W[(size_t)i*ldw+j];
  float wji = transw ? W[(size_t)i*ldw+j] : W[(size_t)j*ldw+i];
  float g = 0.0f;
  for (int ss=0; ss<S; ss++) g += Gp[(size_t)ss*n*n + (size_t)i*n + j];
  Mo[(size_t)i*n + j] = ((i==j)?1.0f:0.0f) + s*(wij - wji) + s2*g;
}

// dst = 2*X - I
template<typename TD>
__global__ void qtop_kernel(const float* __restrict__ X, int n,
                            TD* __restrict__ dst, int ldd){
  int j = blockIdx.x*blockDim.x + threadIdx.x;
  int i = blockIdx.y;
  if (j<n) storeS(&dst[(size_t)i*ldd+j],
                  2.0f*X[(size_t)i*n+j] - ((i==j)?1.0f:0.0f));
}

// fp32 tiled transpose: dst[c][r] = src[r][c]; rows,cols % 32 == 0
__global__ void transposeF_kernel(const float* __restrict__ src, int ls,
                                  float* __restrict__ dst, int ld){
  __shared__ float t[32][33];
  int c0 = blockIdx.x<<5, r0 = blockIdx.y<<5;
  int tx = threadIdx.x & 31, ty = threadIdx.x >> 5;
#pragma unroll
  for (int i=0;i<4;i++) t[ty+i*8][tx] = src[(size_t)(r0+ty+i*8)*ls + c0+tx];
  __syncthreads();
#pragma unroll
  for (int i=0;i<4;i++) dst[(size_t)(c0+ty+i*8)*ld + r0+tx] = t[tx][ty+i*8];
}

// A' = [ bf16(h) | bf16(x) | bf16(x - bf16(x)) ]  (8192 x 2176)
__global__ void pack_A_kernel(const float* __restrict__ h, const float* __restrict__ x,
                              bf16_t* __restrict__ Ap){
  int c = blockIdx.x*blockDim.x + threadIdx.x;
  int m = blockIdx.y;
  if (c >= 2176) return;
  float v;
  if (c < 128)       v = h[(size_t)m*128 + c];
  else if (c < 1152) v = x[(size_t)m*1024 + (c-128)];
  else {
    float xv = x[(size_t)m*1024 + (c-1152)];
    v = xv - bf2f(f2bf(xv));
  }
  Ap[(size_t)m*2176 + c] = f2bf(v);
}

__global__ void dup_kernel(bf16_t* __restrict__ Bp){
  int c = blockIdx.x*blockDim.x + threadIdx.x;   // 0..1023
  int r = blockIdx.y;
  Bp[(size_t)r*2176 + 1152 + c] = Bp[(size_t)r*2176 + 128 + c];
}

__global__ void addvec_kernel(const float* __restrict__ a, const float* __restrict__ b,
                              float* __restrict__ c, int n){
  int i = blockIdx.x*blockDim.x + threadIdx.x;
  if (i<n) c[i] = a[i] + b[i];
}

// simplex-with-floor projection: one wave per row of 128; 30 Newton iters.
__global__ __launch_bounds__(256) void project_kernel(
    const float* __restrict__ ft, const float* __restrict__ h, float* __restrict__ out){
  int row  = (blockIdx.x<<2) + (threadIdx.x>>6);
  int lane = threadIdx.x & 63;
  const float* fr = ft + ((size_t)row<<7);
  const float* hr = h  + ((size_t)row<<7);
  float f0 = fr[lane], f1 = fr[lane+64];
  float l0 = -ALPHA_1*(expf(SIGMA_1*hr[lane])   - 1.0f);
  float l1 = -ALPHA_1*(expf(SIGMA_1*hr[lane+64])- 1.0f);
  float s = f0 + f1;
#pragma unroll
  for (int o=32;o;o>>=1) s += __shfl_xor(s, o);
  float lam = s * (1.0f/128.0f);
  for (int it=0; it<30; it++){
    float a0 = f0 - lam, a1 = f1 - lam;
    float g = fmaxf(a0,l0) + fmaxf(a1,l1);
    float c = (a0>l0 ? 1.0f:0.0f) + (a1>l1 ? 1.0f:0.0f);
#pragma unroll
    for (int o=32;o;o>>=1){ g += __shfl_xor(g,o); c += __shfl_xor(c,o); }
    lam += g / fmaxf(c, 1.0f);
  }
  out[((size_t)row<<7)+lane]    = fmaxf(f0-lam, l0);
  out[((size_t)row<<7)+lane+64] = fmaxf(f1-lam, l1);
}

// ---------------------------------------------------------------------------
// host-side helpers (enqueue only)
// ---------------------------------------------------------------------------
template<typename TC, int RELU>
static inline void mfma_nt(hipStream_t st, int Mm, int Nn, int Kk,
    const bf16_t* A, int lda, const bf16_t* B, int ldb, TC* C, int ldc,
    const float* bias){
  dim3 grid(Nn>>7, Mm>>7);
  mfma_nt_kernel<TC,RELU><<<grid, 256, 0, st>>>(Mm,Nn,Kk,A,lda,B,ldb,C,ldc,bias);
}

template<typename TC>
static inline void fgemm(hipStream_t st, int Mm, int Nn, int Kk,
    const float* A, int lda, const float* Bt, int ldb, TC* C, int ldc,
    float alpha, const float* aptr, float beta){
  dim3 grid(Nn>>7, Mm>>7);
  fgemm_nt_kernel<TC><<<grid, 256, 0, st>>>(Mm,Nn,Kk,A,lda,Bt,ldb,C,ldc,
                                            alpha,aptr,beta, 1<<30);
}

// Ping-pong block Gauss-Jordan inverse (nb even -> result lands back in M).
static void gj_inverse2(hipStream_t st, float* M, float* Mtmp, int n,
                        bf16_t* Gh, bf16_t* Gl, bf16_t* Th, bf16_t* Tl){
  int nb = n >> 7;
  float* cur = M; float* nxt = Mtmp;
  for (int k=0;k<nb;k++){
    gj_prepL_kernel<<<nb, 1024, 0, st>>>(cur, n, k, Gh, Gl, Th, Tl);
    dim3 grid(nb, nb);
    gj_update_kernel<<<grid, 256, 0, st>>>(cur, nxt, n, k, Gh, Gl, Th, Tl);
    float* t = cur; cur = nxt; nxt = t;
  }
}

extern "C" void kernel_launch(void* const* d_in, const int* in_sizes, int n_in,
                              void* d_out, int out_size, void* d_ws, size_t ws_size,
                              hipStream_t stream){
  (void)in_sizes; (void)n_in; (void)out_size; (void)ws_size;
  const float* h    = (const float*)d_in[0];   // 8192x128
  const float* x    = (const float*)d_in[1];   // 8192x1024
  const float* Whm  = (const float*)d_in[2];   // 4096x128
  const float* bhm  = (const float*)d_in[3];
  const float* ahm  = (const float*)d_in[4];
  const float* Wmm  = (const float*)d_in[5];   // 4096x4096
  const float* bmm  = (const float*)d_in[6];
  const float* amm  = (const float*)d_in[7];
  const float* Wmh  = (const float*)d_in[8];   // 128x4096
  const float* bmh  = (const float*)d_in[9];
  const float* amh  = (const float*)d_in[10];
  const float* Wux  = (const float*)d_in[11];  // 4096x1024
  const float* bux  = (const float*)d_in[12];
  const float* auxs = (const float*)d_in[13];
  float* out = (float*)d_out;

  // ---- workspace (~184 MiB peak) ----
  char* wp = (char*)d_ws;
  auto alloc = [&](size_t bytes)->void*{
    void* p = (void*)wp; wp += (bytes + 255) & ~(size_t)255; return p; };
  float*  scal   = (float*)alloc(4096);
  float*  Mhm    = (float*)alloc((size_t)128*128*4);
  float*  Mmh    = (float*)alloc((size_t)128*128*4);
  float*  P128   = (float*)alloc((size_t)128*128*4);
  float*  PT128  = (float*)alloc((size_t)128*128*4);
  bf16_t* GhB    = (bf16_t*)alloc((size_t)32*16384*2);    // 1 MiB
  bf16_t* GlB    = (bf16_t*)alloc((size_t)32*16384*2);    // 1 MiB
  bf16_t* ThB    = (bf16_t*)alloc((size_t)32*16384*2);    // 1 MiB
  bf16_t* TlB    = (bf16_t*)alloc((size_t)32*16384*2);    // 1 MiB
  bf16_t* Qmh_b  = (bf16_t*)alloc((size_t)128*4096*2);    // 1 MiB
  float*  bsum   = (float*)alloc((size_t)4096*4);
  bf16_t* Bp     = (bf16_t*)alloc((size_t)4096*2176*2);   // 17 MiB [Qhm|Qux|Qux_dup]
  float*  R1     = (float*)alloc((size_t)4096*4096*4);    // 64 MiB
  float*  R2     = (float*)alloc((size_t)4096*4096*4);    // 64 MiB
  bf16_t* Qmmb   = (bf16_t*)alloc((size_t)4096*4096*2);   // 32 MiB
  // lifetime aliases:
  float*  gram23 = R1;                          // phases 2/3: 31 Gram partials (~2 MiB)
  float*  WmhTv  = R1 + (size_t)1024*1024;      // phase 3: 3968x128 (disjoint)
  float*  Mmm  = R1;                            // I+A_mm -> inverse (GJ ping-pong R1<->R2)
  bf16_t* Ap   = (bf16_t*)R1;                   // packed A' (after qtop)
  bf16_t* z2   = (bf16_t*)R1;                   // GEMM2 out
  float*  Mux  = R2 + (size_t)1024*1024;        // phase-1 carve of R2
  float*  XuxT = R2 + (size_t)5*1024*1024;      //   4 MiB
  float*  Gp1  = R2 + (size_t)6*1024*1024;      //   16 MiB (4 split-K Gram partials)
  bf16_t* z    = (bf16_t*)R2;                   // GEMM1 out
  float*  ftl  = R2;                            // GEMM3 out (z dead)

  // ---- phase 0: scales s = a/||W||_F
  hipMemsetAsync(scal, 0, 16*sizeof(float), stream);
  sumsq_kernel<<<512,256,0,stream>>>(Whm, 4096*128,  scal+0);
  sumsq_kernel<<<512,256,0,stream>>>(Wmm, 4096*4096, scal+1);
  sumsq_kernel<<<512,256,0,stream>>>(Wmh, 128*4096,  scal+2);
  sumsq_kernel<<<512,256,0,stream>>>(Wux, 4096*1024, scal+3);
  scales_kernel<<<1,1,0,stream>>>(scal, ahm, amm, amh, auxs);

  // ---- phase 1: ux (1024) -> Bp cols [128,1152)
  gram_partial_kernel<0><<<dim3(8,8,4),256,0,stream>>>(
      Wux + (size_t)1024*1024, 1024, 1024, 768, Gp1);     // V = Wux[1024:]
  build_rect_kernel<<<dim3(64,64),256,0,stream>>>(Wux,1024,0,1024, Gp1,4, scal,7,11, Mux);
  gj_inverse2(stream, Mux, R1, 1024, GhB, GlB, ThB, TlB);
  transposeF_kernel<<<dim3(32,32),256,0,stream>>>(Mux, 1024, XuxT, 1024);
  qtop_kernel<bf16_t><<<dim3(4,1024),256,0,stream>>>(Mux, 1024, Bp+128, 2176);
  fgemm<bf16_t>(stream, 3072,1024,1024, Wux+(size_t)1024*1024,1024, XuxT,1024,
                Bp+(size_t)1024*2176+128, 2176, -2.0f,&scal[7], 0.0f);

  // ---- phase 2: hm (128) -> Bp cols [0,128)
  gram_partial_kernel<0><<<dim3(1,1,31),256,0,stream>>>(
      Whm + (size_t)128*128, 128, 128, 128, gram23);      // V = Whm[128:]
  build_rect_kernel<<<dim3(8,8),256,0,stream>>>(Whm,128,0,128, gram23,31, scal,4,8, Mhm);
  invert128_kernel<<<1,1024,0,stream>>>(Mhm,128,P128,PT128);
  qtop_kernel<bf16_t><<<dim3(1,128),256,0,stream>>>(P128, 128, Bp, 2176);
  fgemm<bf16_t>(stream, 3968,128,128, Whm+128*128,128, PT128,128,
                Bp+(size_t)128*2176, 2176, -2.0f,&scal[4], 0.0f);

  // ---- phase 3: mh (via W_mh^T) -> Qmh_b (128x4096)
  gram_partial_kernel<1><<<dim3(1,1,31),256,0,stream>>>(
      Wmh + 128, 4096, 128, 128, gram23);                 // V[kap][i]=Wmh[i][128+kap]
  build_rect_kernel<<<dim3(8,8),256,0,stream>>>(Wmh,4096,1,128, gram23,31, scal,6,10, Mmh);
  invert128_kernel<<<1,1024,0,stream>>>(Mmh,128,P128,PT128);
  qtop_kernel<bf16_t><<<dim3(1,128),256,0,stream>>>(PT128, 128, Qmh_b, 4096);
  transposeF_kernel<<<dim3(124,4),256,0,stream>>>(Wmh+128, 4096, WmhTv, 128);
  fgemm<bf16_t>(stream, 128,3968,128, PT128,128, WmhTv,128,
                Qmh_b+128, 4096, -2.0f,&scal[6], 0.0f);

  // ---- phase 4: mm (4096): GJ inverse ping-pong R1<->R2, then Q = 2X - I
  build_mm_kernel<<<dim3(256,256),256,0,stream>>>(Wmm, scal, Mmm);
  gj_inverse2(stream, Mmm, R2, 4096, GhB, GlB, ThB, TlB);
  qtop_kernel<bf16_t><<<dim3(16,4096),256,0,stream>>>(Mmm, 4096, Qmmb, 4096);
  // R1 now dead -> Ap; R2 free -> z.

  // ---- phase 5: pack A', finish B', bias sum
  pack_A_kernel<<<dim3(9,8192),256,0,stream>>>(h, x, Ap);
  dup_kernel<<<dim3(4,4096),256,0,stream>>>(Bp);
  addvec_kernel<<<16,256,0,stream>>>(bhm, bux, bsum, 4096);

  // ---- phases 6-8: forward (bf16 MFMA)
  mfma_nt<bf16_t,1>(stream, 8192,4096,2176, Ap,2176, Bp,2176, z,4096, bsum);
  mfma_nt<bf16_t,1>(stream, 8192,4096,4096, z,4096, Qmmb,4096, z2,4096, bmm);
  mfma_nt<float,0>(stream, 8192, 128,4096, z2,4096, Qmh_b,4096, ftl,128, bmh);

  // ---- phase 9: projection
  project_kernel<<<2048,256,0,stream>>>(ftl, h, out);
}

// Round 9
// 5695.876 us; speedup vs baseline: 4.5702x; 1.1143x over previous
//
#include <hip/hip_runtime.h>
#include <math.h>

// Problem: B=8192, NH=128, M=4096, XD=1024
#define ALPHA_1 100.0f
#define SIGMA_1 0.02f

typedef unsigned short bf16_t;   // raw bf16 storage
typedef short  bf16x8  __attribute__((ext_vector_type(8)));   // MFMA A/B frag
typedef float  floatx4 __attribute__((ext_vector_type(4)));   // MFMA C/D frag

typedef __attribute__((address_space(1))) void glb_void;
typedef __attribute__((address_space(3))) void lds_void;

__device__ __forceinline__ float bf2f(bf16_t u){ return __uint_as_float(((unsigned)u)<<16); }
__device__ __forceinline__ bf16_t f2bf(float f){
  unsigned u = __float_as_uint(f);
  u += 0x7FFFu + ((u>>16)&1u);          // RNE
  return (bf16_t)(u>>16);
}

// split float4 -> bf16 hi + bf16 residual lo
__device__ __forceinline__ void split4(float4 v, ushort4& h, ushort4& l){
  h.x=f2bf(v.x); h.y=f2bf(v.y); h.z=f2bf(v.z); h.w=f2bf(v.w);
  l.x=f2bf(v.x-bf2f(h.x)); l.y=f2bf(v.y-bf2f(h.y));
  l.z=f2bf(v.z-bf2f(h.z)); l.w=f2bf(v.w-bf2f(h.w));
}

__device__ __forceinline__ float4 load4f(const float* p){ return *(const float4*)p; }
__device__ __forceinline__ float loadS(const float* p){ return *p; }
__device__ __forceinline__ float loadS(const bf16_t* p){ return bf2f(*p); }
__device__ __forceinline__ void storeS(float* p, float v){ *p = v; }
__device__ __forceinline__ void storeS(bf16_t* p, float v){ *p = f2bf(v); }

// async 16B global->LDS (gfx950). LDS side is wave-uniform base + lane*16.
__device__ __forceinline__ void async_copy16(void* lds, const void* g){
  __builtin_amdgcn_global_load_lds((glb_void*)g, (lds_void*)lds, 16, 0, 0);
}

// ---------------------------------------------------------------------------
// bf16 MFMA NT GEMM (forward path): C[M][N] = sum_k A[m][k]*B[n][k] + bias.
// 128x128 tile, BK=64, 4 waves of 64x64. NO XCD swizzle (round-5 A/B:
// chunked swizzle doubled FETCH_SIZE on these L3-resident operands).
// ---------------------------------------------------------------------------
template<typename TC, int RELU>
__global__ __launch_bounds__(256) void mfma_nt_kernel(
    int Mm, int Nn, int Kk,
    const bf16_t* __restrict__ A, int lda,
    const bf16_t* __restrict__ B, int ldb,
    TC* __restrict__ C, int ldc,
    const float* __restrict__ bias)
{
  __shared__ bf16_t As[128*64];
  __shared__ bf16_t Bs[128*64];
  const int tid  = threadIdx.x;
  const int lane = tid & 63, wv = tid >> 6;
  const int m0 = (int)(blockIdx.y << 7), n0 = (int)(blockIdx.x << 7);
  const int wm = (wv >> 1) << 6, wn = (wv & 1) << 6;
  const int rbase = wv << 5;                 // 32 rows per wave

  floatx4 acc[4][4] = {};

  for (int kk = 0; kk < Kk; kk += 64){
    __syncthreads();                         // prev iter's readers done
#pragma unroll
    for (int q=0;q<4;q++){
      int row = rbase + (q<<3) + (lane>>3);
      int cg  = (lane&7) ^ (row&7);          // swizzled global chunk
      async_copy16(&As[(size_t)(rbase+(q<<3))<<6],
                   A + (size_t)(m0+row)*lda + kk + (cg<<3));
      async_copy16(&Bs[(size_t)(rbase+(q<<3))<<6],
                   B + (size_t)(n0+row)*ldb + kk + (cg<<3));
    }
    __syncthreads();
#pragma unroll
    for (int ks=0; ks<2; ks++){
      bf16x8 af[4], bf[4];
      int quad = lane>>4, mr = lane&15;
      int c = quad + (ks<<2);                // chunk 0..7
#pragma unroll
      for (int i=0;i<4;i++){
        int rowa = wm + i*16 + mr;
        af[i] = *(const bf16x8*)&As[(rowa<<6) + ((c ^ (rowa&7))<<3)];
        int rowb = wn + i*16 + mr;
        bf[i] = *(const bf16x8*)&Bs[(rowb<<6) + ((c ^ (rowb&7))<<3)];
      }
#pragma unroll
      for (int i=0;i<4;i++)
#pragma unroll
        for (int j=0;j<4;j++)
          acc[i][j] = __builtin_amdgcn_mfma_f32_16x16x32_bf16(af[i], bf[j], acc[i][j], 0,0,0);
    }
  }
#pragma unroll
  for (int i=0;i<4;i++){
#pragma unroll
    for (int j=0;j<4;j++){
      int rbase2 = m0 + wm + i*16 + (lane>>4)*4;
      int col    = n0 + wn + j*16 + (lane&15);
      float bv = bias ? bias[col] : 0.0f;
#pragma unroll
      for (int r=0;r<4;r++){
        float v = acc[i][j][r] + bv;
        if (RELU) v = fmaxf(v, 0.0f);
        storeS(&C[(size_t)(rbase2+r)*ldc + col], v);
      }
    }
  }
}

// ---------------------------------------------------------------------------
// fp32-precision NT GEMM on matrix cores via bf16 hi/lo split (bf16x3):
// C[M][N] = alpha*(aptr?)*sum_k A[m][k]*Bt[n][k] + beta*C. 128x128 tile, BK=64.
// ---------------------------------------------------------------------------
template<typename TC>
__global__ __launch_bounds__(256) void fgemm_nt_kernel(
    int Mm, int Nn, int Kk,
    const float* __restrict__ A, int lda,
    const float* __restrict__ Bt, int ldb,
    TC* __restrict__ C, int ldc,
    float alpha, const float* __restrict__ alpha_ptr, float beta, int skipk)
{
  __shared__ bf16_t Ah[128*64], Al[128*64], Bh[128*64], Bl[128*64];
  const int tid = threadIdx.x;
  const int lane = tid & 63, wv = tid >> 6;
  int by = blockIdx.y; if (by >= skipk) by++;
  const int m0 = by << 7, n0 = blockIdx.x << 7;
  const int wm = (wv >> 1) << 6, wn = (wv & 1) << 6;
  floatx4 acc[4][4] = {};

  for (int kk = 0; kk < Kk; kk += 64){
    float4 va[8], vb[8];
#pragma unroll
    for (int i=0;i<8;i++){
      int idx = (tid<<3) + i;               // 0..2047
      int row = idx >> 4;                   // 0..127
      int cg  = idx & 15;                   // float4 granule
      va[i] = load4f(A  + (size_t)(m0+row)*lda + kk + (cg<<2));
      vb[i] = load4f(Bt + (size_t)(n0+row)*ldb + kk + (cg<<2));
    }
    __syncthreads();
#pragma unroll
    for (int i=0;i<8;i++){
      int idx = (tid<<3) + i;
      int row = idx >> 4, cg = idx & 15;
      int off = (row<<6) + (((cg>>1) ^ (row&7))<<3) + ((cg&1)<<2);
      ushort4 hv, lv; split4(va[i], hv, lv);
      *(ushort4*)&Ah[off] = hv; *(ushort4*)&Al[off] = lv;
      ushort4 hw, lw; split4(vb[i], hw, lw);
      *(ushort4*)&Bh[off] = hw; *(ushort4*)&Bl[off] = lw;
    }
    __syncthreads();
#pragma unroll
    for (int ks=0; ks<2; ks++){
      int quad = lane>>4, mr = lane&15;
      int c = quad + (ks<<2);
      bf16x8 ah[4], al[4], bh[4], bl[4];
#pragma unroll
      for (int i=0;i<4;i++){
        int rowa = wm + i*16 + mr; int sa = (rowa<<6) + ((c ^ (rowa&7))<<3);
        ah[i] = *(const bf16x8*)&Ah[sa]; al[i] = *(const bf16x8*)&Al[sa];
        int rowb = wn + i*16 + mr; int sb = (rowb<<6) + ((c ^ (rowb&7))<<3);
        bh[i] = *(const bf16x8*)&Bh[sb]; bl[i] = *(const bf16x8*)&Bl[sb];
      }
#pragma unroll
      for (int i=0;i<4;i++)
#pragma unroll
        for (int j=0;j<4;j++){
          acc[i][j] = __builtin_amdgcn_mfma_f32_16x16x32_bf16(ah[i], bl[j], acc[i][j], 0,0,0);
          acc[i][j] = __builtin_amdgcn_mfma_f32_16x16x32_bf16(al[i], bh[j], acc[i][j], 0,0,0);
          acc[i][j] = __builtin_amdgcn_mfma_f32_16x16x32_bf16(ah[i], bh[j], acc[i][j], 0,0,0);
        }
    }
    __syncthreads();
  }
  float am = alpha;
  if (alpha_ptr) am *= *alpha_ptr;
#pragma unroll
  for (int i=0;i<4;i++){
#pragma unroll
    for (int j=0;j<4;j++){
      int rb = m0 + wm + i*16 + (lane>>4)*4;
      int col = n0 + wn + j*16 + (lane&15);
#pragma unroll
      for (int r=0;r<4;r++){
        size_t off = (size_t)(rb+r)*ldc + col;
        float v = am * acc[i][j][r];
        if (beta != 0.0f) v = fmaf(beta, loadS(&C[off]), v);
        storeS(&C[off], v);
      }
    }
  }
}

// ---------------------------------------------------------------------------
// 128x128 Gauss-Jordan inverse (no pivot), 1024 threads, register-resident.
// Writes inverse AND its transpose. (Used standalone by phases 2/3.)
// ---------------------------------------------------------------------------
__global__ __launch_bounds__(1024) void invert128_kernel(
    const float* __restrict__ src, int ld,
    float* __restrict__ dst, float* __restrict__ dstT)
{
  __shared__ float brow[2][8*36];            // [parity][sub*36 + col]
  const int t = threadIdx.x;
  const int r = t>>3, sub = t&7;
  const int lane = t & 63;
  const int cb = (sub&3)<<5;
  const bool isA = sub < 4;
  float own[32];
  if (isA){
#pragma unroll
    for (int i=0;i<32;i++) own[i] = src[(size_t)r*ld + cb + i];
  } else {
#pragma unroll
    for (int i=0;i<32;i++) own[i] = (cb+i == r) ? 1.0f : 0.0f;
  }
  for (int pb=0; pb<4; pb++){
#pragma unroll
    for (int pi=0; pi<32; pi++){
      const int p = (pb<<5) + pi;
      float f = __shfl(own[pi], (lane & 56) | pb);
      float* bw = brow[p & 1];
      if (r == p){
        float ip = 1.0f / f;
#pragma unroll
        for (int i=0;i<32;i++) own[i] *= ip;
#pragma unroll
        for (int i=0;i<8;i++){
          float4 v;
          v.x = own[(i<<2)+0]; v.y = own[(i<<2)+1];
          v.z = own[(i<<2)+2]; v.w = own[(i<<2)+3];
          *(float4*)&bw[sub*36 + (i<<2)] = v;
        }
      }
      __syncthreads();
      if (r != p){
#pragma unroll
        for (int i=0;i<8;i++){
          float4 b = *(const float4*)&bw[sub*36 + (i<<2)];
          own[(i<<2)+0] = fmaf(-f, b.x, own[(i<<2)+0]);
          own[(i<<2)+1] = fmaf(-f, b.y, own[(i<<2)+1]);
          own[(i<<2)+2] = fmaf(-f, b.z, own[(i<<2)+2]);
          own[(i<<2)+3] = fmaf(-f, b.w, own[(i<<2)+3]);
        }
      }
    }
  }
  if (!isA){
#pragma unroll
    for (int i=0;i<32;i++){
      dst [(size_t)r*128 + cb + i] = own[i];
      dstT[(size_t)(cb+i)*128 + r] = own[i];
    }
  }
}

// ===========================================================================
// Block Gauss-Jordan inverse: overlap topology (round-4, correctness-proven)
// with the PROVEN 1024-thread prep body (round-5/8) — the 256-thr preps that
// failed in r4/r6 are gone. All GJ kernels are 1024-thread.
// Per step k (ping-pong Min -> Mout):
//   stepA (2nb-1 blocks): update only col k+1 and row k+1 tiles.
//   stepB (nb + (nb-1)^2 blocks): blocks [0,nb) run prep1024(k+1) reading
//     Mout's fresh col/row k+1 (stepA output); the rest update the remaining
//     tiles. Disjoint reads/writes -> race-free within the dispatch.
// G,T stored pre-split bf16 hi/lo (2 parities); update staging = pure copy.
// ===========================================================================

// --- proven prepL body, shared memory passed in (brow 2304B | Pl 66KB | Ast 66KB)
__device__ void prep1024(
    const float* __restrict__ Mc, int n, int k, int ib,
    bf16_t* __restrict__ Gh, bf16_t* __restrict__ Gl,
    bf16_t* __restrict__ Th, bf16_t* __restrict__ Tl,
    char* smraw, int t)
{
  float* browB = (float*)smraw;              // [2][288]
  float* Pl    = (float*)(smraw + 2304);     // 128*132 floats
  float* Ast   = (float*)(smraw + 69888);    // 128*132 floats
  const int r = t>>3, sub = t&7;
  const int lane = t & 63;
  const int cb = (sub&3)<<5;
  const bool isA = sub < 4;
  const float* D = Mc + ((size_t)(k<<7))*n + (k<<7);
  float own[32];
  if (isA){
#pragma unroll
    for (int q=0;q<32;q++) own[q] = D[(size_t)r*n + cb + q];
  } else {
#pragma unroll
    for (int q=0;q<32;q++) own[q] = (cb+q == r) ? 1.0f : 0.0f;
  }
  for (int pb=0; pb<4; pb++){
#pragma unroll
    for (int pi=0; pi<32; pi++){
      const int p = (pb<<5) + pi;
      float f = __shfl(own[pi], (lane & 56) | pb);
      float* bw = browB + (p & 1)*288;
      if (r == p){
        float ip = 1.0f / f;
#pragma unroll
        for (int q=0;q<32;q++) own[q] *= ip;
#pragma unroll
        for (int q=0;q<8;q++){
          float4 v;
          v.x=own[(q<<2)+0]; v.y=own[(q<<2)+1]; v.z=own[(q<<2)+2]; v.w=own[(q<<2)+3];
          *(float4*)&bw[sub*36 + (q<<2)] = v;
        }
      }
      __syncthreads();
      if (r != p){
#pragma unroll
        for (int q=0;q<8;q++){
          float4 b = *(const float4*)&bw[sub*36 + (q<<2)];
          own[(q<<2)+0] = fmaf(-f, b.x, own[(q<<2)+0]);
          own[(q<<2)+1] = fmaf(-f, b.y, own[(q<<2)+1]);
          own[(q<<2)+2] = fmaf(-f, b.z, own[(q<<2)+2]);
          own[(q<<2)+3] = fmaf(-f, b.w, own[(q<<2)+3]);
        }
      }
    }
  }
  // publish P to LDS (and G[k] = P, hi/lo, if this is the pivot-row block)
  if (!isA){
#pragma unroll
    for (int q=0;q<8;q++){
      float4 v;
      v.x=own[(q<<2)+0]; v.y=own[(q<<2)+1]; v.z=own[(q<<2)+2]; v.w=own[(q<<2)+3];
      *(float4*)&Pl[r*132 + cb + (q<<2)] = v;
      if (ib == k){
        ushort4 hv, lv; split4(v, hv, lv);
        *(ushort4*)&Gh[((size_t)k<<14) + (r<<7) + cb + (q<<2)] = hv;
        *(ushort4*)&Gl[((size_t)k<<14) + (r<<7) + cb + (q<<2)] = lv;
      }
    }
  }
  __syncthreads();
  if (ib == k) return;

  // ---- T[ib] = transpose of tile (k, ib), via LDS staging, hi/lo stores
  const float* Ski = Mc + ((size_t)(k<<7))*n + (ib<<7);
#pragma unroll
  for (int q=0;q<4;q++){
    int f4 = (t<<2) + q;                 // 0..4095
    int rr = f4>>5, c4 = (f4&31)<<2;
    *(float4*)&Ast[rr*132 + c4] = *(const float4*)&Ski[(size_t)rr*n + c4];
  }
  __syncthreads();
#pragma unroll
  for (int q=0;q<4;q++){
    int f4 = (t<<2) + q;
    int cc = f4>>5, r4 = (f4&31)<<2;
    float4 v;
    v.x = Ast[(r4+0)*132 + cc]; v.y = Ast[(r4+1)*132 + cc];
    v.z = Ast[(r4+2)*132 + cc]; v.w = Ast[(r4+3)*132 + cc];
    ushort4 hv, lv; split4(v, hv, lv);
    *(ushort4*)&Th[((size_t)ib<<14) + (cc<<7) + r4] = hv;
    *(ushort4*)&Tl[((size_t)ib<<14) + (cc<<7) + r4] = lv;
  }
  __syncthreads();

  // ---- Ast = tile (ib, k)
  const float* Sik = Mc + ((size_t)(ib<<7))*n + (k<<7);
#pragma unroll
  for (int q=0;q<4;q++){
    int f4 = (t<<2) + q;
    int rr = f4>>5, c4 = (f4&31)<<2;
    *(float4*)&Ast[rr*132 + c4] = *(const float4*)&Sik[(size_t)rr*n + c4];
  }
  __syncthreads();

  // ---- G[ib] = -(Ast * P), fp32, 4x4 per thread, hi/lo stores
  const int tx = t&31, ty = t>>5;
  const int r0 = ty<<2, c0 = tx<<2;
  float acc[4][4] = {};
  for (int kq=0; kq<128; kq++){
    float4 b = *(const float4*)&Pl[kq*132 + c0];
    float a0 = Ast[(r0+0)*132 + kq];
    float a1 = Ast[(r0+1)*132 + kq];
    float a2 = Ast[(r0+2)*132 + kq];
    float a3 = Ast[(r0+3)*132 + kq];
    acc[0][0]=fmaf(a0,b.x,acc[0][0]); acc[0][1]=fmaf(a0,b.y,acc[0][1]);
    acc[0][2]=fmaf(a0,b.z,acc[0][2]); acc[0][3]=fmaf(a0,b.w,acc[0][3]);
    acc[1][0]=fmaf(a1,b.x,acc[1][0]); acc[1][1]=fmaf(a1,b.y,acc[1][1]);
    acc[1][2]=fmaf(a1,b.z,acc[1][2]); acc[1][3]=fmaf(a1,b.w,acc[1][3]);
    acc[2][0]=fmaf(a2,b.x,acc[2][0]); acc[2][1]=fmaf(a2,b.y,acc[2][1]);
    acc[2][2]=fmaf(a2,b.z,acc[2][2]); acc[2][3]=fmaf(a2,b.w,acc[2][3]);
    acc[3][0]=fmaf(a3,b.x,acc[3][0]); acc[3][1]=fmaf(a3,b.y,acc[3][1]);
    acc[3][2]=fmaf(a3,b.z,acc[3][2]); acc[3][3]=fmaf(a3,b.w,acc[3][3]);
  }
#pragma unroll
  for (int rr=0;rr<4;rr++){
    float4 v; v.x=-acc[rr][0]; v.y=-acc[rr][1]; v.z=-acc[rr][2]; v.w=-acc[rr][3];
    ushort4 hv, lv; split4(v, hv, lv);
    *(ushort4*)&Gh[((size_t)ib<<14) + ((size_t)(r0+rr)<<7) + c0] = hv;
    *(ushort4*)&Gl[((size_t)ib<<14) + ((size_t)(r0+rr)<<7) + c0] = lv;
  }
}

// --- 1024-thread update tile: 16 waves x 32x32 output; same swizzle/staging
// formulas as the proven 256-thr version (per-wave structure identical).
// Mout(by,bx) = (bx==k) ? G[by] : (by!=k)*Min + G[by]*T[bx]^T
__device__ void update_tile1024(
    const float* __restrict__ Min, float* __restrict__ Mout, int n, int k,
    int by, int bx,
    const bf16_t* __restrict__ Gh, const bf16_t* __restrict__ Gl,
    const bf16_t* __restrict__ Th, const bf16_t* __restrict__ Tl,
    char* sm, int tid)
{
  if (bx == k){
    const bf16_t* sh = Gh + ((size_t)by<<14);
    const bf16_t* sl = Gl + ((size_t)by<<14);
    float* dst = Mout + ((size_t)(by<<7))*n + ((size_t)k<<7);
    for (int q=tid; q<4096; q+=1024){
      int r=q>>5, c4=(q&31)<<2;
      ushort4 hv=*(const ushort4*)&sh[(r<<7)+c4];
      ushort4 lv=*(const ushort4*)&sl[(r<<7)+c4];
      float4 v; v.x=bf2f(hv.x)+bf2f(lv.x); v.y=bf2f(hv.y)+bf2f(lv.y);
                v.z=bf2f(hv.z)+bf2f(lv.z); v.w=bf2f(hv.w)+bf2f(lv.w);
      *(float4*)&dst[(size_t)r*n + c4] = v;
    }
    return;
  }
  bf16_t* Ah=(bf16_t*)sm;           bf16_t* Al=(bf16_t*)(sm+16384);
  bf16_t* Bh=(bf16_t*)(sm+32768);   bf16_t* Bl=(bf16_t*)(sm+49152);
  const int lane = tid & 63, wv = tid >> 6;          // 16 waves
  const int wm = (wv >> 2) << 5, wn = (wv & 3) << 5; // 4x4 grid of 32x32
  const bf16_t* gh = Gh + ((size_t)by<<14);
  const bf16_t* gl = Gl + ((size_t)by<<14);
  const bf16_t* th = Th + ((size_t)bx<<14);
  const bf16_t* tl = Tl + ((size_t)bx<<14);
  floatx4 acc[2][2] = {};

#pragma unroll
  for (int kk = 0; kk < 128; kk += 64){
    __syncthreads();
#pragma unroll
    for (int s=0;s<2;s++){
      int idx = tid + (s<<10);              // 0..2047 ushort4 granules
      int row = idx >> 4, cg = idx & 15;
      int off = (row<<6) + (((cg>>1) ^ (row&7))<<3) + ((cg&1)<<2);
      *(ushort4*)&Ah[off] = *(const ushort4*)&gh[(row<<7) + kk + (cg<<2)];
      *(ushort4*)&Al[off] = *(const ushort4*)&gl[(row<<7) + kk + (cg<<2)];
      *(ushort4*)&Bh[off] = *(const ushort4*)&th[(row<<7) + kk + (cg<<2)];
      *(ushort4*)&Bl[off] = *(const ushort4*)&tl[(row<<7) + kk + (cg<<2)];
    }
    __syncthreads();
#pragma unroll
    for (int ks=0; ks<2; ks++){
      int quad = lane>>4, mr = lane&15;
      int c = quad + (ks<<2);
      bf16x8 ah[2], al[2], bh[2], bl[2];
#pragma unroll
      for (int i=0;i<2;i++){
        int rowa = wm + i*16 + mr; int sa = (rowa<<6) + ((c ^ (rowa&7))<<3);
        ah[i] = *(const bf16x8*)&Ah[sa]; al[i] = *(const bf16x8*)&Al[sa];
        int rowb = wn + i*16 + mr; int sb = (rowb<<6) + ((c ^ (rowb&7))<<3);
        bh[i] = *(const bf16x8*)&Bh[sb]; bl[i] = *(const bf16x8*)&Bl[sb];
      }
#pragma unroll
      for (int i=0;i<2;i++)
#pragma unroll
        for (int j=0;j<2;j++){
          acc[i][j] = __builtin_amdgcn_mfma_f32_16x16x32_bf16(ah[i], bl[j], acc[i][j], 0,0,0);
          acc[i][j] = __builtin_amdgcn_mfma_f32_16x16x32_bf16(al[i], bh[j], acc[i][j], 0,0,0);
          acc[i][j] = __builtin_amdgcn_mfma_f32_16x16x32_bf16(ah[i], bh[j], acc[i][j], 0,0,0);
        }
    }
  }
  const int addin = (by != k);
#pragma unroll
  for (int i=0;i<2;i++)
#pragma unroll
    for (int j=0;j<2;j++){
      int rb = (by<<7) + wm + i*16 + ((lane>>4)<<2);
      int col = (bx<<7) + wn + j*16 + (lane&15);
#pragma unroll
      for (int r4=0;r4<4;r4++){
        size_t off = (size_t)(rb+r4)*n + col;
        float v = acc[i][j][r4];
        if (addin) v += Min[off];
        Mout[off] = v;
      }
    }
}

// standalone prep(0): nb blocks x 1024 thr
__global__ __launch_bounds__(1024) void gj_prep0_kernel(
    const float* __restrict__ M, int n,
    bf16_t* Gh, bf16_t* Gl, bf16_t* Th, bf16_t* Tl)
{
  __shared__ char sm[137472] __attribute__((aligned(16)));
  prep1024(M, n, 0, blockIdx.x, Gh, Gl, Th, Tl, sm, threadIdx.x);
}

// stepA: update col k+1 (all by) and row k+1 (bx != k+1). grid 2nb-1.
__global__ __launch_bounds__(1024) void gj_stepA_kernel(
    const float* __restrict__ Min, float* __restrict__ Mout, int n, int k,
    const bf16_t* __restrict__ Gh, const bf16_t* __restrict__ Gl,
    const bf16_t* __restrict__ Th, const bf16_t* __restrict__ Tl)
{
  __shared__ char sm[65536] __attribute__((aligned(16)));
  const int nb = n >> 7;
  const int bid = blockIdx.x;
  int by, bx;
  if (bid < nb){ by = bid; bx = k+1; }
  else { by = k+1; bx = bid-nb; if (bx >= k+1) bx++; }
  update_tile1024(Min, Mout, n, k, by, bx, Gh, Gl, Th, Tl, sm, threadIdx.x);
}

// stepB: blocks [0,nb) run prep1024(k+1) from Mout; rest update the
// remaining (nb-1)^2 tiles (by,bx != k+1). grid nb + (nb-1)^2.
__global__ __launch_bounds__(1024) void gj_stepB_kernel(
    const float* __restrict__ Min, float* __restrict__ Mout, int n, int k,
    const bf16_t* __restrict__ Gh, const bf16_t* __restrict__ Gl,
    const bf16_t* __restrict__ Th, const bf16_t* __restrict__ Tl,
    bf16_t* Gnh, bf16_t* Gnl, bf16_t* Tnh, bf16_t* Tnl)
{
  __shared__ char sm[137472] __attribute__((aligned(16)));
  const int nb = n >> 7;
  const int bid = blockIdx.x, tid = threadIdx.x;
  if (bid < nb){
    prep1024(Mout, n, k+1, bid, Gnh, Gnl, Tnh, Tnl, sm, tid);
  } else {
    int q = bid - nb;
    int by = q/(nb-1), bx = q - by*(nb-1);
    if (by >= k+1) by++;
    if (bx >= k+1) bx++;
    update_tile1024(Min, Mout, n, k, by, bx, Gh, Gl, Th, Tl, sm, tid);
  }
}

// last step: all nb*nb tiles, no prep. grid nb*nb.
__global__ __launch_bounds__(1024) void gj_stepL_kernel(
    const float* __restrict__ Min, float* __restrict__ Mout, int n, int k,
    const bf16_t* __restrict__ Gh, const bf16_t* __restrict__ Gl,
    const bf16_t* __restrict__ Th, const bf16_t* __restrict__ Tl)
{
  __shared__ char sm[65536] __attribute__((aligned(16)));
  const int nb = n >> 7;
  int by = blockIdx.x / nb, bx = blockIdx.x - by*nb;
  update_tile1024(Min, Mout, n, k, by, bx, Gh, Gl, Th, Tl, sm, threadIdx.x);
}

// ---------------------------------------------------------------------------
// Split-K Gram partials: Gp[z][i][j] = sum_{kappa in slice z} V[kappa][i]*V[kappa][j]
// ---------------------------------------------------------------------------
template<int TRANS>
__global__ __launch_bounds__(256) void gram_partial_kernel(
    const float* __restrict__ V, int ldv, int n, int Ks,
    float* __restrict__ Gp)
{
  __shared__ float Vi[16][132];
  __shared__ float Vj[16][132];
  const int cj = blockIdx.x, ci = blockIdx.y, z = blockIdx.z;
  const int tid = threadIdx.x;
  const int i0 = ci<<7, j0 = cj<<7;
  const int tx = tid&15, ty = tid>>4;
  float acc[8][8] = {};
  for (int k0 = z*Ks; k0 < (z+1)*Ks; k0 += 16){
    if (TRANS == 0){
      for (int q=tid; q<512; q+=256){
        int kr = q>>5, c4 = (q&31)<<2;
        *(float4*)&Vi[kr][c4] = *(const float4*)&V[(size_t)(k0+kr)*ldv + i0 + c4];
        *(float4*)&Vj[kr][c4] = *(const float4*)&V[(size_t)(k0+kr)*ldv + j0 + c4];
      }
    } else {
      for (int q=tid; q<512; q+=256){
        int c = q>>2, qq = (q&3)<<2;
        float4 a = *(const float4*)&V[(size_t)(i0+c)*ldv + k0 + qq];
        Vi[qq+0][c]=a.x; Vi[qq+1][c]=a.y; Vi[qq+2][c]=a.z; Vi[qq+3][c]=a.w;
        float4 b = *(const float4*)&V[(size_t)(j0+c)*ldv + k0 + qq];
        Vj[qq+0][c]=b.x; Vj[qq+1][c]=b.y; Vj[qq+2][c]=b.z; Vj[qq+3][c]=b.w;
      }
    }
    __syncthreads();
#pragma unroll
    for (int kr=0; kr<16; kr++){
      float a[8], b[8];
      *(float4*)&a[0] = *(const float4*)&Vi[kr][(ty<<3)];
      *(float4*)&a[4] = *(const float4*)&Vi[kr][(ty<<3)+4];
      *(float4*)&b[0] = *(const float4*)&Vj[kr][(tx<<3)];
      *(float4*)&b[4] = *(const float4*)&Vj[kr][(tx<<3)+4];
#pragma unroll
      for (int i=0;i<8;i++)
#pragma unroll
        for (int jj=0;jj<8;jj++) acc[i][jj] = fmaf(a[i], b[jj], acc[i][jj]);
    }
    __syncthreads();
  }
#pragma unroll
  for (int i=0;i<8;i++)
#pragma unroll
    for (int jj=0;jj<8;jj++)
      Gp[(size_t)z*n*n + (size_t)(i0+(ty<<3)+i)*n + j0+(tx<<3)+jj] = acc[i][jj];
}

// ---------------------------------------------------------------------------
// small kernels
// ---------------------------------------------------------------------------
__global__ void sumsq_kernel(const float* __restrict__ w, int n, float* __restrict__ acc){
  float s = 0.0f;
  for (int i = blockIdx.x*blockDim.x + threadIdx.x; i < n; i += gridDim.x*blockDim.x){
    float v = w[i]; s = fmaf(v, v, s);
  }
#pragma unroll
  for (int o=32;o;o>>=1) s += __shfl_xor(s, o);
  if ((threadIdx.x & 63) == 0) atomicAdd(acc, s);
}

__global__ void scales_kernel(float* scal, const float* a0, const float* a1,
                              const float* a2, const float* a3){
  if (threadIdx.x==0 && blockIdx.x==0){
    float s;
    s = a0[0]/sqrtf(scal[0]); scal[4]=s; scal[8]=s*s;
    s = a1[0]/sqrtf(scal[1]); scal[5]=s; scal[9]=s*s;
    s = a2[0]/sqrtf(scal[2]); scal[6]=s; scal[10]=s*s;
    s = a3[0]/sqrtf(scal[3]); scal[7]=s; scal[11]=s*s;
  }
}

__global__ void build_mm_kernel(const float* __restrict__ W, const float* __restrict__ scal,
                                float* __restrict__ Mo){
  int j = (blockIdx.x<<4) + (threadIdx.x&15);
  int i = (blockIdx.y<<4) + (threadIdx.x>>4);
  float s = scal[5];
  float a = s*(W[((size_t)i<<12)+j] - W[((size_t)j<<12)+i]);
  Mo[((size_t)i<<12)+j] = ((i==j)?1.0f:0.0f) + a;
}

// Mo = I + s*(W - W^T) + s2 * sum_s Gp[s]
__global__ void build_rect_kernel(const float* __restrict__ W, int ldw, int transw, int n,
      const float* __restrict__ Gp, int S,
      const float* __restrict__ scal, int sidx, int sidx2,
      float* __restrict__ Mo){
  int j = (blockIdx.x<<4)+(threadIdx.x&15);
  int i = (blockIdx.y<<4)+(threadIdx.x>>4);
  float s = scal[sidx], s2 = scal[sidx2];
  float wij = transw ? W[(size_t)j*ldw+i] : W[(size_t)i*ldw+j];
  float wji = transw ? W[(size_t)i*ldw+j] : W[(size_t)j*ldw+i];
  float g = 0.0f;
  for (int ss=0; ss<S; ss++) g += Gp[(size_t)ss*n*n + (size_t)i*n + j];
  Mo[(size_t)i*n + j] = ((i==j)?1.0f:0.0f) + s*(wij - wji) + s2*g;
}

// dst = 2*X - I
template<typename TD>
__global__ void qtop_kernel(const float* __restrict__ X, int n,
                            TD* __restrict__ dst, int ldd){
  int j = blockIdx.x*blockDim.x + threadIdx.x;
  int i = blockIdx.y;
  if (j<n) storeS(&dst[(size_t)i*ldd+j],
                  2.0f*X[(size_t)i*n+j] - ((i==j)?1.0f:0.0f));
}

// fp32 tiled transpose: dst[c][r] = src[r][c]; rows,cols % 32 == 0
__global__ void transposeF_kernel(const float* __restrict__ src, int ls,
                                  float* __restrict__ dst, int ld){
  __shared__ float t[32][33];
  int c0 = blockIdx.x<<5, r0 = blockIdx.y<<5;
  int tx = threadIdx.x & 31, ty = threadIdx.x >> 5;
#pragma unroll
  for (int i=0;i<4;i++) t[ty+i*8][tx] = src[(size_t)(r0+ty+i*8)*ls + c0+tx];
  __syncthreads();
#pragma unroll
  for (int i=0;i<4;i++) dst[(size_t)(c0+ty+i*8)*ld + r0+tx] = t[tx][ty+i*8];
}

// A' = [ bf16(h) | bf16(x) | bf16(x - bf16(x)) ]  (8192 x 2176)
__global__ void pack_A_kernel(const float* __restrict__ h, const float* __restrict__ x,
                              bf16_t* __restrict__ Ap){
  int c = blockIdx.x*blockDim.x + threadIdx.x;
  int m = blockIdx.y;
  if (c >= 2176) return;
  float v;
  if (c < 128)       v = h[(size_t)m*128 + c];
  else if (c < 1152) v = x[(size_t)m*1024 + (c-128)];
  else {
    float xv = x[(size_t)m*1024 + (c-1152)];
    v = xv - bf2f(f2bf(xv));
  }
  Ap[(size_t)m*2176 + c] = f2bf(v);
}

__global__ void dup_kernel(bf16_t* __restrict__ Bp){
  int c = blockIdx.x*blockDim.x + threadIdx.x;   // 0..1023
  int r = blockIdx.y;
  Bp[(size_t)r*2176 + 1152 + c] = Bp[(size_t)r*2176 + 128 + c];
}

__global__ void addvec_kernel(const float* __restrict__ a, const float* __restrict__ b,
                              float* __restrict__ c, int n){
  int i = blockIdx.x*blockDim.x + threadIdx.x;
  if (i<n) c[i] = a[i] + b[i];
}

// simplex-with-floor projection: one wave per row of 128; 30 Newton iters.
__global__ __launch_bounds__(256) void project_kernel(
    const float* __restrict__ ft, const float* __restrict__ h, float* __restrict__ out){
  int row  = (blockIdx.x<<2) + (threadIdx.x>>6);
  int lane = threadIdx.x & 63;
  const float* fr = ft + ((size_t)row<<7);
  const float* hr = h  + ((size_t)row<<7);
  float f0 = fr[lane], f1 = fr[lane+64];
  float l0 = -ALPHA_1*(expf(SIGMA_1*hr[lane])   - 1.0f);
  float l1 = -ALPHA_1*(expf(SIGMA_1*hr[lane+64])- 1.0f);
  float s = f0 + f1;
#pragma unroll
  for (int o=32;o;o>>=1) s += __shfl_xor(s, o);
  float lam = s * (1.0f/128.0f);
  for (int it=0; it<30; it++){
    float a0 = f0 - lam, a1 = f1 - lam;
    float g = fmaxf(a0,l0) + fmaxf(a1,l1);
    float c = (a0>l0 ? 1.0f:0.0f) + (a1>l1 ? 1.0f:0.0f);
#pragma unroll
    for (int o=32;o;o>>=1){ g += __shfl_xor(g,o); c += __shfl_xor(c,o); }
    lam += g / fmaxf(c, 1.0f);
  }
  out[((size_t)row<<7)+lane]    = fmaxf(f0-lam, l0);
  out[((size_t)row<<7)+lane+64] = fmaxf(f1-lam, l1);
}

// ---------------------------------------------------------------------------
// host-side helpers (enqueue only)
// ---------------------------------------------------------------------------
template<typename TC, int RELU>
static inline void mfma_nt(hipStream_t st, int Mm, int Nn, int Kk,
    const bf16_t* A, int lda, const bf16_t* B, int ldb, TC* C, int ldc,
    const float* bias){
  dim3 grid(Nn>>7, Mm>>7);
  mfma_nt_kernel<TC,RELU><<<grid, 256, 0, st>>>(Mm,Nn,Kk,A,lda,B,ldb,C,ldc,bias);
}

template<typename TC>
static inline void fgemm(hipStream_t st, int Mm, int Nn, int Kk,
    const float* A, int lda, const float* Bt, int ldb, TC* C, int ldc,
    float alpha, const float* aptr, float beta){
  dim3 grid(Nn>>7, Mm>>7);
  fgemm_nt_kernel<TC><<<grid, 256, 0, st>>>(Mm,Nn,Kk,A,lda,Bt,ldb,C,ldc,
                                            alpha,aptr,beta, 1<<30);
}

// Ping-pong block Gauss-Jordan inverse; nb even -> result lands back in M.
// prep0; per step {stepA; stepB(with overlapped prep1024(k+1))}; last stepL.
static void gj_inverse4(hipStream_t st, float* M, float* Mtmp, int n,
    bf16_t* Gh, bf16_t* Gl, bf16_t* Th, bf16_t* Tl){
  const int nb = n >> 7;
  const size_t gstep = (size_t)nb << 14;
  gj_prep0_kernel<<<nb, 1024, 0, st>>>(M, n, Gh, Gl, Th, Tl);   // parity 0
  for (int k=0; k<nb; k++){
    const float* Min = (k&1) ? Mtmp : M;
    float* Mout      = (k&1) ? M : Mtmp;
    const size_t pc = (size_t)(k&1)*gstep, pn = (size_t)((k&1)^1)*gstep;
    if (k < nb-1){
      gj_stepA_kernel<<<2*nb-1, 1024, 0, st>>>(Min, Mout, n, k,
          Gh+pc, Gl+pc, Th+pc, Tl+pc);
      gj_stepB_kernel<<<nb + (nb-1)*(nb-1), 1024, 0, st>>>(Min, Mout, n, k,
          Gh+pc, Gl+pc, Th+pc, Tl+pc,
          Gh+pn, Gl+pn, Th+pn, Tl+pn);
    } else {
      gj_stepL_kernel<<<nb*nb, 1024, 0, st>>>(Min, Mout, n, k,
          Gh+pc, Gl+pc, Th+pc, Tl+pc);
    }
  }
}

extern "C" void kernel_launch(void* const* d_in, const int* in_sizes, int n_in,
                              void* d_out, int out_size, void* d_ws, size_t ws_size,
                              hipStream_t stream){
  (void)in_sizes; (void)n_in; (void)out_size; (void)ws_size;
  const float* h    = (const float*)d_in[0];   // 8192x128
  const float* x    = (const float*)d_in[1];   // 8192x1024
  const float* Whm  = (const float*)d_in[2];   // 4096x128
  const float* bhm  = (const float*)d_in[3];
  const float* ahm  = (const float*)d_in[4];
  const float* Wmm  = (const float*)d_in[5];   // 4096x4096
  const float* bmm  = (const float*)d_in[6];
  const float* amm  = (const float*)d_in[7];
  const float* Wmh  = (const float*)d_in[8];   // 128x4096
  const float* bmh  = (const float*)d_in[9];
  const float* amh  = (const float*)d_in[10];
  const float* Wux  = (const float*)d_in[11];  // 4096x1024
  const float* bux  = (const float*)d_in[12];
  const float* auxs = (const float*)d_in[13];
  float* out = (float*)d_out;

  // ---- workspace (~188 MiB peak; 189 MiB proven safe) ----
  char* wp = (char*)d_ws;
  auto alloc = [&](size_t bytes)->void*{
    void* p = (void*)wp; wp += (bytes + 255) & ~(size_t)255; return p; };
  float*  scal   = (float*)alloc(4096);
  float*  Mhm    = (float*)alloc((size_t)128*128*4);
  float*  Mmh    = (float*)alloc((size_t)128*128*4);
  float*  P128   = (float*)alloc((size_t)128*128*4);
  float*  PT128  = (float*)alloc((size_t)128*128*4);
  bf16_t* GhB    = (bf16_t*)alloc((size_t)2*32*16384*2);  // 2 MiB (2 parities)
  bf16_t* GlB    = (bf16_t*)alloc((size_t)2*32*16384*2);  // 2 MiB
  bf16_t* ThB    = (bf16_t*)alloc((size_t)2*32*16384*2);  // 2 MiB
  bf16_t* TlB    = (bf16_t*)alloc((size_t)2*32*16384*2);  // 2 MiB
  bf16_t* Qmh_b  = (bf16_t*)alloc((size_t)128*4096*2);    // 1 MiB
  float*  bsum   = (float*)alloc((size_t)4096*4);
  bf16_t* Bp     = (bf16_t*)alloc((size_t)4096*2176*2);   // 17 MiB [Qhm|Qux|Qux_dup]
  float*  R1     = (float*)alloc((size_t)4096*4096*4);    // 64 MiB
  float*  R2     = (float*)alloc((size_t)4096*4096*4);    // 64 MiB
  bf16_t* Qmmb   = (bf16_t*)alloc((size_t)4096*4096*2);   // 32 MiB
  // lifetime aliases:
  float*  gram23 = R1;                          // phases 2/3: 31 Gram partials (~2 MiB)
  float*  WmhTv  = R1 + (size_t)1024*1024;      // phase 3: 3968x128 (disjoint)
  float*  Mmm  = R1;                            // I+A_mm -> inverse (GJ ping-pong R1<->R2)
  bf16_t* Ap   = (bf16_t*)R1;                   // packed A' (after qtop)
  bf16_t* z2   = (bf16_t*)R1;                   // GEMM2 out
  float*  Mux  = R2 + (size_t)1024*1024;        // phase-1 carve of R2
  float*  XuxT = R2 + (size_t)5*1024*1024;      //   4 MiB
  float*  Gp1  = R2 + (size_t)6*1024*1024;      //   16 MiB (4 split-K Gram partials)
  bf16_t* z    = (bf16_t*)R2;                   // GEMM1 out
  float*  ftl  = R2;                            // GEMM3 out (z dead)

  // ---- phase 0: scales s = a/||W||_F
  hipMemsetAsync(scal, 0, 16*sizeof(float), stream);
  sumsq_kernel<<<512,256,0,stream>>>(Whm, 4096*128,  scal+0);
  sumsq_kernel<<<512,256,0,stream>>>(Wmm, 4096*4096, scal+1);
  sumsq_kernel<<<512,256,0,stream>>>(Wmh, 128*4096,  scal+2);
  sumsq_kernel<<<512,256,0,stream>>>(Wux, 4096*1024, scal+3);
  scales_kernel<<<1,1,0,stream>>>(scal, ahm, amm, amh, auxs);

  // ---- phase 1: ux (1024) -> Bp cols [128,1152)
  gram_partial_kernel<0><<<dim3(8,8,4),256,0,stream>>>(
      Wux + (size_t)1024*1024, 1024, 1024, 768, Gp1);     // V = Wux[1024:]
  build_rect_kernel<<<dim3(64,64),256,0,stream>>>(Wux,1024,0,1024, Gp1,4, scal,7,11, Mux);
  gj_inverse4(stream, Mux, R1, 1024, GhB, GlB, ThB, TlB);
  transposeF_kernel<<<dim3(32,32),256,0,stream>>>(Mux, 1024, XuxT, 1024);
  qtop_kernel<bf16_t><<<dim3(4,1024),256,0,stream>>>(Mux, 1024, Bp+128, 2176);
  fgemm<bf16_t>(stream, 3072,1024,1024, Wux+(size_t)1024*1024,1024, XuxT,1024,
                Bp+(size_t)1024*2176+128, 2176, -2.0f,&scal[7], 0.0f);

  // ---- phase 2: hm (128) -> Bp cols [0,128)
  gram_partial_kernel<0><<<dim3(1,1,31),256,0,stream>>>(
      Whm + (size_t)128*128, 128, 128, 128, gram23);      // V = Whm[128:]
  build_rect_kernel<<<dim3(8,8),256,0,stream>>>(Whm,128,0,128, gram23,31, scal,4,8, Mhm);
  invert128_kernel<<<1,1024,0,stream>>>(Mhm,128,P128,PT128);
  qtop_kernel<bf16_t><<<dim3(1,128),256,0,stream>>>(P128, 128, Bp, 2176);
  fgemm<bf16_t>(stream, 3968,128,128, Whm+128*128,128, PT128,128,
                Bp+(size_t)128*2176, 2176, -2.0f,&scal[4], 0.0f);

  // ---- phase 3: mh (via W_mh^T) -> Qmh_b (128x4096)
  gram_partial_kernel<1><<<dim3(1,1,31),256,0,stream>>>(
      Wmh + 128, 4096, 128, 128, gram23);                 // V[kap][i]=Wmh[i][128+kap]
  build_rect_kernel<<<dim3(8,8),256,0,stream>>>(Wmh,4096,1,128, gram23,31, scal,6,10, Mmh);
  invert128_kernel<<<1,1024,0,stream>>>(Mmh,128,P128,PT128);
  qtop_kernel<bf16_t><<<dim3(1,128),256,0,stream>>>(PT128, 128, Qmh_b, 4096);
  transposeF_kernel<<<dim3(124,4),256,0,stream>>>(Wmh+128, 4096, WmhTv, 128);
  fgemm<bf16_t>(stream, 128,3968,128, PT128,128, WmhTv,128,
                Qmh_b+128, 4096, -2.0f,&scal[6], 0.0f);

  // ---- phase 4: mm (4096): GJ inverse ping-pong R1<->R2, then Q = 2X - I
  build_mm_kernel<<<dim3(256,256),256,0,stream>>>(Wmm, scal, Mmm);
  gj_inverse4(stream, Mmm, R2, 4096, GhB, GlB, ThB, TlB);
  qtop_kernel<bf16_t><<<dim3(16,4096),256,0,stream>>>(Mmm, 4096, Qmmb, 4096);
  // R1 now dead -> Ap; R2 free -> z.

  // ---- phase 5: pack A', finish B', bias sum
  pack_A_kernel<<<dim3(9,8192),256,0,stream>>>(h, x, Ap);
  dup_kernel<<<dim3(4,4096),256,0,stream>>>(Bp);
  addvec_kernel<<<16,256,0,stream>>>(bhm, bux, bsum, 4096);

  // ---- phases 6-8: forward (bf16 MFMA)
  mfma_nt<bf16_t,1>(stream, 8192,4096,2176, Ap,2176, Bp,2176, z,4096, bsum);
  mfma_nt<bf16_t,1>(stream, 8192,4096,4096, z,4096, Qmmb,4096, z2,4096, bmm);
  mfma_nt<float,0>(stream, 8192, 128,4096, z2,4096, Qmh_b,4096, ftl,128, bmh);

  // ---- phase 9: projection
  project_kernel<<<2048,256,0,stream>>>(ftl, h, out);
}

// Round 10
// 5111.406 us; speedup vs baseline: 5.0928x; 1.1143x over previous
//
#include <hip/hip_runtime.h>
#include <math.h>

// Problem: B=8192, NH=128, M=4096, XD=1024
#define ALPHA_1 100.0f
#define SIGMA_1 0.02f

typedef unsigned short bf16_t;   // raw bf16 storage
typedef short  bf16x8  __attribute__((ext_vector_type(8)));   // MFMA A/B frag
typedef float  floatx4 __attribute__((ext_vector_type(4)));   // MFMA C/D frag

typedef __attribute__((address_space(1))) void glb_void;
typedef __attribute__((address_space(3))) void lds_void;

__device__ __forceinline__ float bf2f(bf16_t u){ return __uint_as_float(((unsigned)u)<<16); }
__device__ __forceinline__ bf16_t f2bf(float f){
  unsigned u = __float_as_uint(f);
  u += 0x7FFFu + ((u>>16)&1u);          // RNE
  return (bf16_t)(u>>16);
}

// split float4 -> bf16 hi + bf16 residual lo
__device__ __forceinline__ void split4(float4 v, ushort4& h, ushort4& l){
  h.x=f2bf(v.x); h.y=f2bf(v.y); h.z=f2bf(v.z); h.w=f2bf(v.w);
  l.x=f2bf(v.x-bf2f(h.x)); l.y=f2bf(v.y-bf2f(h.y));
  l.z=f2bf(v.z-bf2f(h.z)); l.w=f2bf(v.w-bf2f(h.w));
}

__device__ __forceinline__ float4 load4f(const float* p){ return *(const float4*)p; }
__device__ __forceinline__ float loadS(const float* p){ return *p; }
__device__ __forceinline__ float loadS(const bf16_t* p){ return bf2f(*p); }
__device__ __forceinline__ void storeS(float* p, float v){ *p = v; }
__device__ __forceinline__ void storeS(bf16_t* p, float v){ *p = f2bf(v); }

// async 16B global->LDS (gfx950). LDS side is wave-uniform base + lane*16.
__device__ __forceinline__ void async_copy16(void* lds, const void* g){
  __builtin_amdgcn_global_load_lds((glb_void*)g, (lds_void*)lds, 16, 0, 0);
}

// ---------------------------------------------------------------------------
// bf16 MFMA NT GEMM (forward path): C[M][N] = sum_k A[m][k]*B[n][k] + bias.
// 128x128 tile, BK=64, 4 waves of 64x64. NO XCD swizzle (round-5 A/B:
// chunked swizzle doubled FETCH_SIZE on these L3-resident operands).
// ---------------------------------------------------------------------------
template<typename TC, int RELU>
__global__ __launch_bounds__(256) void mfma_nt_kernel(
    int Mm, int Nn, int Kk,
    const bf16_t* __restrict__ A, int lda,
    const bf16_t* __restrict__ B, int ldb,
    TC* __restrict__ C, int ldc,
    const float* __restrict__ bias)
{
  __shared__ bf16_t As[128*64];
  __shared__ bf16_t Bs[128*64];
  const int tid  = threadIdx.x;
  const int lane = tid & 63, wv = tid >> 6;
  const int m0 = (int)(blockIdx.y << 7), n0 = (int)(blockIdx.x << 7);
  const int wm = (wv >> 1) << 6, wn = (wv & 1) << 6;
  const int rbase = wv << 5;                 // 32 rows per wave

  floatx4 acc[4][4] = {};

  for (int kk = 0; kk < Kk; kk += 64){
    __syncthreads();                         // prev iter's readers done
#pragma unroll
    for (int q=0;q<4;q++){
      int row = rbase + (q<<3) + (lane>>3);
      int cg  = (lane&7) ^ (row&7);          // swizzled global chunk
      async_copy16(&As[(size_t)(rbase+(q<<3))<<6],
                   A + (size_t)(m0+row)*lda + kk + (cg<<3));
      async_copy16(&Bs[(size_t)(rbase+(q<<3))<<6],
                   B + (size_t)(n0+row)*ldb + kk + (cg<<3));
    }
    __syncthreads();
#pragma unroll
    for (int ks=0; ks<2; ks++){
      bf16x8 af[4], bf[4];
      int quad = lane>>4, mr = lane&15;
      int c = quad + (ks<<2);                // chunk 0..7
#pragma unroll
      for (int i=0;i<4;i++){
        int rowa = wm + i*16 + mr;
        af[i] = *(const bf16x8*)&As[(rowa<<6) + ((c ^ (rowa&7))<<3)];
        int rowb = wn + i*16 + mr;
        bf[i] = *(const bf16x8*)&Bs[(rowb<<6) + ((c ^ (rowb&7))<<3)];
      }
#pragma unroll
      for (int i=0;i<4;i++)
#pragma unroll
        for (int j=0;j<4;j++)
          acc[i][j] = __builtin_amdgcn_mfma_f32_16x16x32_bf16(af[i], bf[j], acc[i][j], 0,0,0);
    }
  }
#pragma unroll
  for (int i=0;i<4;i++){
#pragma unroll
    for (int j=0;j<4;j++){
      int rbase2 = m0 + wm + i*16 + (lane>>4)*4;
      int col    = n0 + wn + j*16 + (lane&15);
      float bv = bias ? bias[col] : 0.0f;
#pragma unroll
      for (int r=0;r<4;r++){
        float v = acc[i][j][r] + bv;
        if (RELU) v = fmaxf(v, 0.0f);
        storeS(&C[(size_t)(rbase2+r)*ldc + col], v);
      }
    }
  }
}

// ---------------------------------------------------------------------------
// fp32-precision NT GEMM on matrix cores via bf16 hi/lo split (bf16x3):
// C[M][N] = alpha*(aptr?)*sum_k A[m][k]*Bt[n][k] + beta*C. 128x128 tile, BK=64.
// ---------------------------------------------------------------------------
template<typename TC>
__global__ __launch_bounds__(256) void fgemm_nt_kernel(
    int Mm, int Nn, int Kk,
    const float* __restrict__ A, int lda,
    const float* __restrict__ Bt, int ldb,
    TC* __restrict__ C, int ldc,
    float alpha, const float* __restrict__ alpha_ptr, float beta, int skipk)
{
  __shared__ bf16_t Ah[128*64], Al[128*64], Bh[128*64], Bl[128*64];
  const int tid = threadIdx.x;
  const int lane = tid & 63, wv = tid >> 6;
  int by = blockIdx.y; if (by >= skipk) by++;
  const int m0 = by << 7, n0 = blockIdx.x << 7;
  const int wm = (wv >> 1) << 6, wn = (wv & 1) << 6;
  floatx4 acc[4][4] = {};

  for (int kk = 0; kk < Kk; kk += 64){
    float4 va[8], vb[8];
#pragma unroll
    for (int i=0;i<8;i++){
      int idx = (tid<<3) + i;               // 0..2047
      int row = idx >> 4;                   // 0..127
      int cg  = idx & 15;                   // float4 granule
      va[i] = load4f(A  + (size_t)(m0+row)*lda + kk + (cg<<2));
      vb[i] = load4f(Bt + (size_t)(n0+row)*ldb + kk + (cg<<2));
    }
    __syncthreads();
#pragma unroll
    for (int i=0;i<8;i++){
      int idx = (tid<<3) + i;
      int row = idx >> 4, cg = idx & 15;
      int off = (row<<6) + (((cg>>1) ^ (row&7))<<3) + ((cg&1)<<2);
      ushort4 hv, lv; split4(va[i], hv, lv);
      *(ushort4*)&Ah[off] = hv; *(ushort4*)&Al[off] = lv;
      ushort4 hw, lw; split4(vb[i], hw, lw);
      *(ushort4*)&Bh[off] = hw; *(ushort4*)&Bl[off] = lw;
    }
    __syncthreads();
#pragma unroll
    for (int ks=0; ks<2; ks++){
      int quad = lane>>4, mr = lane&15;
      int c = quad + (ks<<2);
      bf16x8 ah[4], al[4], bh[4], bl[4];
#pragma unroll
      for (int i=0;i<4;i++){
        int rowa = wm + i*16 + mr; int sa = (rowa<<6) + ((c ^ (rowa&7))<<3);
        ah[i] = *(const bf16x8*)&Ah[sa]; al[i] = *(const bf16x8*)&Al[sa];
        int rowb = wn + i*16 + mr; int sb = (rowb<<6) + ((c ^ (rowb&7))<<3);
        bh[i] = *(const bf16x8*)&Bh[sb]; bl[i] = *(const bf16x8*)&Bl[sb];
      }
#pragma unroll
      for (int i=0;i<4;i++)
#pragma unroll
        for (int j=0;j<4;j++){
          acc[i][j] = __builtin_amdgcn_mfma_f32_16x16x32_bf16(ah[i], bl[j], acc[i][j], 0,0,0);
          acc[i][j] = __builtin_amdgcn_mfma_f32_16x16x32_bf16(al[i], bh[j], acc[i][j], 0,0,0);
          acc[i][j] = __builtin_amdgcn_mfma_f32_16x16x32_bf16(ah[i], bh[j], acc[i][j], 0,0,0);
        }
    }
    __syncthreads();
  }
  float am = alpha;
  if (alpha_ptr) am *= *alpha_ptr;
#pragma unroll
  for (int i=0;i<4;i++){
#pragma unroll
    for (int j=0;j<4;j++){
      int rb = m0 + wm + i*16 + (lane>>4)*4;
      int col = n0 + wn + j*16 + (lane&15);
#pragma unroll
      for (int r=0;r<4;r++){
        size_t off = (size_t)(rb+r)*ldc + col;
        float v = am * acc[i][j][r];
        if (beta != 0.0f) v = fmaf(beta, loadS(&C[off]), v);
        storeS(&C[off], v);
      }
    }
  }
}

// ---------------------------------------------------------------------------
// 128x128 Gauss-Jordan inverse (no pivot), 1024 threads, register-resident.
// Writes inverse AND its transpose. (Used standalone by phases 2/3.)
// ---------------------------------------------------------------------------
__global__ __launch_bounds__(1024) void invert128_kernel(
    const float* __restrict__ src, int ld,
    float* __restrict__ dst, float* __restrict__ dstT)
{
  __shared__ float brow[2][8*36];            // [parity][sub*36 + col]
  const int t = threadIdx.x;
  const int r = t>>3, sub = t&7;
  const int lane = t & 63;
  const int cb = (sub&3)<<5;
  const bool isA = sub < 4;
  float own[32];
  if (isA){
#pragma unroll
    for (int i=0;i<32;i++) own[i] = src[(size_t)r*ld + cb + i];
  } else {
#pragma unroll
    for (int i=0;i<32;i++) own[i] = (cb+i == r) ? 1.0f : 0.0f;
  }
  for (int pb=0; pb<4; pb++){
#pragma unroll
    for (int pi=0; pi<32; pi++){
      const int p = (pb<<5) + pi;
      float f = __shfl(own[pi], (lane & 56) | pb);
      float* bw = brow[p & 1];
      if (r == p){
        float ip = 1.0f / f;
#pragma unroll
        for (int i=0;i<32;i++) own[i] *= ip;
#pragma unroll
        for (int i=0;i<8;i++){
          float4 v;
          v.x = own[(i<<2)+0]; v.y = own[(i<<2)+1];
          v.z = own[(i<<2)+2]; v.w = own[(i<<2)+3];
          *(float4*)&bw[sub*36 + (i<<2)] = v;
        }
      }
      __syncthreads();
      if (r != p){
#pragma unroll
        for (int i=0;i<8;i++){
          float4 b = *(const float4*)&bw[sub*36 + (i<<2)];
          own[(i<<2)+0] = fmaf(-f, b.x, own[(i<<2)+0]);
          own[(i<<2)+1] = fmaf(-f, b.y, own[(i<<2)+1]);
          own[(i<<2)+2] = fmaf(-f, b.z, own[(i<<2)+2]);
          own[(i<<2)+3] = fmaf(-f, b.w, own[(i<<2)+3]);
        }
      }
    }
  }
  if (!isA){
#pragma unroll
    for (int i=0;i<32;i++){
      dst [(size_t)r*128 + cb + i] = own[i];
      dstT[(size_t)(cb+i)*128 + r] = own[i];
    }
  }
}

// ===========================================================================
// Block Gauss-Jordan inverse, ONE dispatch per step:
//   gj_stepF (nb + nb*nb blocks x 1024 thr):
//     blocks [0,nb): prep for pivot k+1. Instead of reading stepA's output,
//       each prep block RECOMPUTES the updated tiles it needs — (k+1,k+1),
//       (k+1,ib), (ib,k+1) — from Min + G/T via the same bf16x3 MFMA the
//       update uses (bit-identical values), into LDS. Then: register-GJ
//       inverse, T'[ib] transpose-store, G'[ib] = -(Gsrc * P) — all the
//       PROVEN 1024-thread bodies from rounds 5/8/9.
//     blocks [nb,...): update ALL nb*nb tiles of Mout (stepL body).
//   Disjoint writes (prep -> G/T parity pn; update -> Mout), prep reads only
//   Min + G/T(pc) -> race-free. Last step: gj_stepL only.
// ===========================================================================

// compute updated tile (r,c) of step k into LDS fp32 Dst[128*132].
// Dst must not alias stage. Ends with a barrier (Dst readable on return).
__device__ void tile_to_lds(
    const float* __restrict__ Min, int n, int k, int r, int c,
    const bf16_t* __restrict__ Gh, const bf16_t* __restrict__ Gl,
    const bf16_t* __restrict__ Th, const bf16_t* __restrict__ Tl,
    float* __restrict__ Dst, char* __restrict__ stage, int tid)
{
  if (c == k){                    // column k: decode G[r] hi+lo
    const bf16_t* sh = Gh + ((size_t)r<<14);
    const bf16_t* sl = Gl + ((size_t)r<<14);
    for (int q=tid; q<4096; q+=1024){
      int rr=q>>5, c4=(q&31)<<2;
      ushort4 hv=*(const ushort4*)&sh[(rr<<7)+c4];
      ushort4 lv=*(const ushort4*)&sl[(rr<<7)+c4];
      Dst[rr*132+c4+0]=bf2f(hv.x)+bf2f(lv.x);
      Dst[rr*132+c4+1]=bf2f(hv.y)+bf2f(lv.y);
      Dst[rr*132+c4+2]=bf2f(hv.z)+bf2f(lv.z);
      Dst[rr*132+c4+3]=bf2f(hv.w)+bf2f(lv.w);
    }
    __syncthreads();
    return;
  }
  bf16_t* Ah=(bf16_t*)stage;           bf16_t* Al=(bf16_t*)(stage+16384);
  bf16_t* Bh=(bf16_t*)(stage+32768);   bf16_t* Bl=(bf16_t*)(stage+49152);
  const int lane = tid & 63, wv = tid >> 6;          // 16 waves
  const int wm = (wv >> 2) << 5, wn = (wv & 3) << 5; // 4x4 grid of 32x32
  const bf16_t* gh = Gh + ((size_t)r<<14);
  const bf16_t* gl = Gl + ((size_t)r<<14);
  const bf16_t* th = Th + ((size_t)c<<14);
  const bf16_t* tl = Tl + ((size_t)c<<14);
  floatx4 acc[2][2] = {};
#pragma unroll
  for (int kk = 0; kk < 128; kk += 64){
    __syncthreads();
#pragma unroll
    for (int s=0;s<2;s++){
      int idx = tid + (s<<10);
      int row = idx >> 4, cg = idx & 15;
      int off = (row<<6) + (((cg>>1) ^ (row&7))<<3) + ((cg&1)<<2);
      *(ushort4*)&Ah[off] = *(const ushort4*)&gh[(row<<7) + kk + (cg<<2)];
      *(ushort4*)&Al[off] = *(const ushort4*)&gl[(row<<7) + kk + (cg<<2)];
      *(ushort4*)&Bh[off] = *(const ushort4*)&th[(row<<7) + kk + (cg<<2)];
      *(ushort4*)&Bl[off] = *(const ushort4*)&tl[(row<<7) + kk + (cg<<2)];
    }
    __syncthreads();
#pragma unroll
    for (int ks=0; ks<2; ks++){
      int quad = lane>>4, mr = lane&15;
      int cc = quad + (ks<<2);
      bf16x8 ah[2], al[2], bh[2], bl[2];
#pragma unroll
      for (int i=0;i<2;i++){
        int rowa = wm + i*16 + mr; int sa = (rowa<<6) + ((cc ^ (rowa&7))<<3);
        ah[i] = *(const bf16x8*)&Ah[sa]; al[i] = *(const bf16x8*)&Al[sa];
        int rowb = wn + i*16 + mr; int sb = (rowb<<6) + ((cc ^ (rowb&7))<<3);
        bh[i] = *(const bf16x8*)&Bh[sb]; bl[i] = *(const bf16x8*)&Bl[sb];
      }
#pragma unroll
      for (int i=0;i<2;i++)
#pragma unroll
        for (int j=0;j<2;j++){
          acc[i][j] = __builtin_amdgcn_mfma_f32_16x16x32_bf16(ah[i], bl[j], acc[i][j], 0,0,0);
          acc[i][j] = __builtin_amdgcn_mfma_f32_16x16x32_bf16(al[i], bh[j], acc[i][j], 0,0,0);
          acc[i][j] = __builtin_amdgcn_mfma_f32_16x16x32_bf16(ah[i], bh[j], acc[i][j], 0,0,0);
        }
    }
  }
  const int addin = (r != k);
#pragma unroll
  for (int i=0;i<2;i++)
#pragma unroll
    for (int j=0;j<2;j++){
      int rb = wm + i*16 + ((lane>>4)<<2);
      int col = wn + j*16 + (lane&15);
#pragma unroll
      for (int r4=0;r4<4;r4++){
        float v = acc[i][j][r4];
        if (addin) v += Min[(size_t)((r<<7)+rb+r4)*n + (c<<7) + col];
        Dst[(rb+r4)*132 + col] = v;
      }
    }
  __syncthreads();
}

// --- proven prep body (round-5/8/9), D/T/Gsrc tiles from global memory.
// shared layout: brow 2304B | Pl 66KB | Ast 66KB. Used by prep0 only.
__device__ void prep1024(
    const float* __restrict__ Mc, int n, int k, int ib,
    bf16_t* __restrict__ Gh, bf16_t* __restrict__ Gl,
    bf16_t* __restrict__ Th, bf16_t* __restrict__ Tl,
    char* smraw, int t)
{
  float* browB = (float*)smraw;              // [2][288]
  float* Pl    = (float*)(smraw + 2304);     // 128*132 floats
  float* Ast   = (float*)(smraw + 69888);    // 128*132 floats
  const int r = t>>3, sub = t&7;
  const int lane = t & 63;
  const int cb = (sub&3)<<5;
  const bool isA = sub < 4;
  const float* D = Mc + ((size_t)(k<<7))*n + (k<<7);
  float own[32];
  if (isA){
#pragma unroll
    for (int q=0;q<32;q++) own[q] = D[(size_t)r*n + cb + q];
  } else {
#pragma unroll
    for (int q=0;q<32;q++) own[q] = (cb+q == r) ? 1.0f : 0.0f;
  }
  for (int pb=0; pb<4; pb++){
#pragma unroll
    for (int pi=0; pi<32; pi++){
      const int p = (pb<<5) + pi;
      float f = __shfl(own[pi], (lane & 56) | pb);
      float* bw = browB + (p & 1)*288;
      if (r == p){
        float ip = 1.0f / f;
#pragma unroll
        for (int q=0;q<32;q++) own[q] *= ip;
#pragma unroll
        for (int q=0;q<8;q++){
          float4 v;
          v.x=own[(q<<2)+0]; v.y=own[(q<<2)+1]; v.z=own[(q<<2)+2]; v.w=own[(q<<2)+3];
          *(float4*)&bw[sub*36 + (q<<2)] = v;
        }
      }
      __syncthreads();
      if (r != p){
#pragma unroll
        for (int q=0;q<8;q++){
          float4 b = *(const float4*)&bw[sub*36 + (q<<2)];
          own[(q<<2)+0] = fmaf(-f, b.x, own[(q<<2)+0]);
          own[(q<<2)+1] = fmaf(-f, b.y, own[(q<<2)+1]);
          own[(q<<2)+2] = fmaf(-f, b.z, own[(q<<2)+2]);
          own[(q<<2)+3] = fmaf(-f, b.w, own[(q<<2)+3]);
        }
      }
    }
  }
  if (!isA){
#pragma unroll
    for (int q=0;q<8;q++){
      float4 v;
      v.x=own[(q<<2)+0]; v.y=own[(q<<2)+1]; v.z=own[(q<<2)+2]; v.w=own[(q<<2)+3];
      *(float4*)&Pl[r*132 + cb + (q<<2)] = v;
      if (ib == k){
        ushort4 hv, lv; split4(v, hv, lv);
        *(ushort4*)&Gh[((size_t)k<<14) + (r<<7) + cb + (q<<2)] = hv;
        *(ushort4*)&Gl[((size_t)k<<14) + (r<<7) + cb + (q<<2)] = lv;
      }
    }
  }
  __syncthreads();
  if (ib == k) return;

  // ---- T[ib] = transpose of tile (k, ib), via LDS staging, hi/lo stores
  const float* Ski = Mc + ((size_t)(k<<7))*n + (ib<<7);
#pragma unroll
  for (int q=0;q<4;q++){
    int f4 = (t<<2) + q;                 // 0..4095
    int rr = f4>>5, c4 = (f4&31)<<2;
    *(float4*)&Ast[rr*132 + c4] = *(const float4*)&Ski[(size_t)rr*n + c4];
  }
  __syncthreads();
#pragma unroll
  for (int q=0;q<4;q++){
    int f4 = (t<<2) + q;
    int cc = f4>>5, r4 = (f4&31)<<2;
    float4 v;
    v.x = Ast[(r4+0)*132 + cc]; v.y = Ast[(r4+1)*132 + cc];
    v.z = Ast[(r4+2)*132 + cc]; v.w = Ast[(r4+3)*132 + cc];
    ushort4 hv, lv; split4(v, hv, lv);
    *(ushort4*)&Th[((size_t)ib<<14) + (cc<<7) + r4] = hv;
    *(ushort4*)&Tl[((size_t)ib<<14) + (cc<<7) + r4] = lv;
  }
  __syncthreads();

  // ---- Ast = tile (ib, k)
  const float* Sik = Mc + ((size_t)(ib<<7))*n + (k<<7);
#pragma unroll
  for (int q=0;q<4;q++){
    int f4 = (t<<2) + q;
    int rr = f4>>5, c4 = (f4&31)<<2;
    *(float4*)&Ast[rr*132 + c4] = *(const float4*)&Sik[(size_t)rr*n + c4];
  }
  __syncthreads();

  // ---- G[ib] = -(Ast * P), fp32, 4x4 per thread, hi/lo stores
  const int tx = t&31, ty = t>>5;
  const int r0 = ty<<2, c0 = tx<<2;
  float acc[4][4] = {};
  for (int kq=0; kq<128; kq++){
    float4 b = *(const float4*)&Pl[kq*132 + c0];
    float a0 = Ast[(r0+0)*132 + kq];
    float a1 = Ast[(r0+1)*132 + kq];
    float a2 = Ast[(r0+2)*132 + kq];
    float a3 = Ast[(r0+3)*132 + kq];
    acc[0][0]=fmaf(a0,b.x,acc[0][0]); acc[0][1]=fmaf(a0,b.y,acc[0][1]);
    acc[0][2]=fmaf(a0,b.z,acc[0][2]); acc[0][3]=fmaf(a0,b.w,acc[0][3]);
    acc[1][0]=fmaf(a1,b.x,acc[1][0]); acc[1][1]=fmaf(a1,b.y,acc[1][1]);
    acc[1][2]=fmaf(a1,b.z,acc[1][2]); acc[1][3]=fmaf(a1,b.w,acc[1][3]);
    acc[2][0]=fmaf(a2,b.x,acc[2][0]); acc[2][1]=fmaf(a2,b.y,acc[2][1]);
    acc[2][2]=fmaf(a2,b.z,acc[2][2]); acc[2][3]=fmaf(a2,b.w,acc[2][3]);
    acc[3][0]=fmaf(a3,b.x,acc[3][0]); acc[3][1]=fmaf(a3,b.y,acc[3][1]);
    acc[3][2]=fmaf(a3,b.z,acc[3][2]); acc[3][3]=fmaf(a3,b.w,acc[3][3]);
  }
#pragma unroll
  for (int rr=0;rr<4;rr++){
    float4 v; v.x=-acc[rr][0]; v.y=-acc[rr][1]; v.z=-acc[rr][2]; v.w=-acc[rr][3];
    ushort4 hv, lv; split4(v, hv, lv);
    *(ushort4*)&Gh[((size_t)ib<<14) + ((size_t)(r0+rr)<<7) + c0] = hv;
    *(ushort4*)&Gl[((size_t)ib<<14) + ((size_t)(r0+rr)<<7) + c0] = lv;
  }
}

// --- fused prep for pivot kp=k+1: recomputes its input tiles from Min+G/T(pc)
// via tile_to_lds (bit-identical to what the update writes), then the proven
// inverse / transpose-store / G-GEMM bodies. Writes G/T parity pn.
__device__ void prep_fused(
    const float* __restrict__ Min, int n, int k, int ib,
    const bf16_t* __restrict__ Gh, const bf16_t* __restrict__ Gl,
    const bf16_t* __restrict__ Th, const bf16_t* __restrict__ Tl,
    bf16_t* __restrict__ Gnh, bf16_t* __restrict__ Gnl,
    bf16_t* __restrict__ Tnh, bf16_t* __restrict__ Tnl,
    char* smraw, int t)
{
  const int kp = k+1;
  float* browB = (float*)smraw;              // [2][288]
  float* Pl    = (float*)(smraw + 2304);     // 128*132 floats (66KB)
  float* Ast   = (float*)(smraw + 69888);    // 128*132 floats (66KB)
  char*  stage = (char*)(smraw + 2304);      // 64KB GEMM staging (aliases Pl)

  // 1. D' = updated tile (kp,kp) -> Ast
  tile_to_lds(Min, n, k, kp, kp, Gh, Gl, Th, Tl, Ast, stage, t);

  // 2. register-GJ inverse of Ast (proven body)
  const int r = t>>3, sub = t&7;
  const int lane = t & 63;
  const int cb = (sub&3)<<5;
  const bool isA = sub < 4;
  float own[32];
  if (isA){
#pragma unroll
    for (int q=0;q<8;q++)
      *(float4*)&own[q<<2] = *(const float4*)&Ast[r*132 + cb + (q<<2)];
  } else {
#pragma unroll
    for (int q=0;q<32;q++) own[q] = (cb+q == r) ? 1.0f : 0.0f;
  }
  __syncthreads();
  for (int pb=0; pb<4; pb++){
#pragma unroll
    for (int pi=0; pi<32; pi++){
      const int p = (pb<<5) + pi;
      float f = __shfl(own[pi], (lane & 56) | pb);
      float* bw = browB + (p & 1)*288;
      if (r == p){
        float ip = 1.0f / f;
#pragma unroll
        for (int q=0;q<32;q++) own[q] *= ip;
#pragma unroll
        for (int q=0;q<8;q++){
          float4 v;
          v.x=own[(q<<2)+0]; v.y=own[(q<<2)+1]; v.z=own[(q<<2)+2]; v.w=own[(q<<2)+3];
          *(float4*)&bw[sub*36 + (q<<2)] = v;
        }
      }
      __syncthreads();
      if (r != p){
#pragma unroll
        for (int q=0;q<8;q++){
          float4 b = *(const float4*)&bw[sub*36 + (q<<2)];
          own[(q<<2)+0] = fmaf(-f, b.x, own[(q<<2)+0]);
          own[(q<<2)+1] = fmaf(-f, b.y, own[(q<<2)+1]);
          own[(q<<2)+2] = fmaf(-f, b.z, own[(q<<2)+2]);
          own[(q<<2)+3] = fmaf(-f, b.w, own[(q<<2)+3]);
        }
      }
    }
  }
  if (ib == kp){
    if (!isA){
#pragma unroll
      for (int q=0;q<8;q++){
        float4 v;
        v.x=own[(q<<2)+0]; v.y=own[(q<<2)+1]; v.z=own[(q<<2)+2]; v.w=own[(q<<2)+3];
        ushort4 hv, lv; split4(v, hv, lv);
        *(ushort4*)&Gnh[((size_t)kp<<14) + (r<<7) + cb + (q<<2)] = hv;
        *(ushort4*)&Gnl[((size_t)kp<<14) + (r<<7) + cb + (q<<2)] = lv;
      }
    }
    return;
  }

  // 3. T'-source = updated tile (kp, ib) -> Ast ; 4. transpose-store -> Tn
  tile_to_lds(Min, n, k, kp, ib, Gh, Gl, Th, Tl, Ast, stage, t);
#pragma unroll
  for (int q=0;q<4;q++){
    int f4 = (t<<2) + q;
    int cc = f4>>5, r4 = (f4&31)<<2;
    float4 v;
    v.x = Ast[(r4+0)*132 + cc]; v.y = Ast[(r4+1)*132 + cc];
    v.z = Ast[(r4+2)*132 + cc]; v.w = Ast[(r4+3)*132 + cc];
    ushort4 hv, lv; split4(v, hv, lv);
    *(ushort4*)&Tnh[((size_t)ib<<14) + (cc<<7) + r4] = hv;
    *(ushort4*)&Tnl[((size_t)ib<<14) + (cc<<7) + r4] = lv;
  }
  __syncthreads();

  // 5. Gsrc = updated tile (ib, kp) -> Ast
  tile_to_lds(Min, n, k, ib, kp, Gh, Gl, Th, Tl, Ast, stage, t);

  // 6. publish P -> Pl (staging dead now)
  if (!isA){
#pragma unroll
    for (int q=0;q<8;q++){
      float4 v;
      v.x=own[(q<<2)+0]; v.y=own[(q<<2)+1]; v.z=own[(q<<2)+2]; v.w=own[(q<<2)+3];
      *(float4*)&Pl[r*132 + cb + (q<<2)] = v;
    }
  }
  __syncthreads();

  // 7. G'[ib] = -(Ast * P), fp32, hi/lo stores (proven tail)
  const int tx = t&31, ty = t>>5;
  const int r0 = ty<<2, c0 = tx<<2;
  float acc[4][4] = {};
  for (int kq=0; kq<128; kq++){
    float4 b = *(const float4*)&Pl[kq*132 + c0];
    float a0 = Ast[(r0+0)*132 + kq];
    float a1 = Ast[(r0+1)*132 + kq];
    float a2 = Ast[(r0+2)*132 + kq];
    float a3 = Ast[(r0+3)*132 + kq];
    acc[0][0]=fmaf(a0,b.x,acc[0][0]); acc[0][1]=fmaf(a0,b.y,acc[0][1]);
    acc[0][2]=fmaf(a0,b.z,acc[0][2]); acc[0][3]=fmaf(a0,b.w,acc[0][3]);
    acc[1][0]=fmaf(a1,b.x,acc[1][0]); acc[1][1]=fmaf(a1,b.y,acc[1][1]);
    acc[1][2]=fmaf(a1,b.z,acc[1][2]); acc[1][3]=fmaf(a1,b.w,acc[1][3]);
    acc[2][0]=fmaf(a2,b.x,acc[2][0]); acc[2][1]=fmaf(a2,b.y,acc[2][1]);
    acc[2][2]=fmaf(a2,b.z,acc[2][2]); acc[2][3]=fmaf(a2,b.w,acc[2][3]);
    acc[3][0]=fmaf(a3,b.x,acc[3][0]); acc[3][1]=fmaf(a3,b.y,acc[3][1]);
    acc[3][2]=fmaf(a3,b.z,acc[3][2]); acc[3][3]=fmaf(a3,b.w,acc[3][3]);
  }
#pragma unroll
  for (int rr=0;rr<4;rr++){
    float4 v; v.x=-acc[rr][0]; v.y=-acc[rr][1]; v.z=-acc[rr][2]; v.w=-acc[rr][3];
    ushort4 hv, lv; split4(v, hv, lv);
    *(ushort4*)&Gnh[((size_t)ib<<14) + ((size_t)(r0+rr)<<7) + c0] = hv;
    *(ushort4*)&Gnl[((size_t)ib<<14) + ((size_t)(r0+rr)<<7) + c0] = lv;
  }
}

// --- 1024-thread update tile (round-9 proven).
// Mout(by,bx) = (bx==k) ? G[by] : (by!=k)*Min + G[by]*T[bx]^T
__device__ void update_tile1024(
    const float* __restrict__ Min, float* __restrict__ Mout, int n, int k,
    int by, int bx,
    const bf16_t* __restrict__ Gh, const bf16_t* __restrict__ Gl,
    const bf16_t* __restrict__ Th, const bf16_t* __restrict__ Tl,
    char* sm, int tid)
{
  if (bx == k){
    const bf16_t* sh = Gh + ((size_t)by<<14);
    const bf16_t* sl = Gl + ((size_t)by<<14);
    float* dst = Mout + ((size_t)(by<<7))*n + ((size_t)k<<7);
    for (int q=tid; q<4096; q+=1024){
      int r=q>>5, c4=(q&31)<<2;
      ushort4 hv=*(const ushort4*)&sh[(r<<7)+c4];
      ushort4 lv=*(const ushort4*)&sl[(r<<7)+c4];
      float4 v; v.x=bf2f(hv.x)+bf2f(lv.x); v.y=bf2f(hv.y)+bf2f(lv.y);
                v.z=bf2f(hv.z)+bf2f(lv.z); v.w=bf2f(hv.w)+bf2f(lv.w);
      *(float4*)&dst[(size_t)r*n + c4] = v;
    }
    return;
  }
  bf16_t* Ah=(bf16_t*)sm;           bf16_t* Al=(bf16_t*)(sm+16384);
  bf16_t* Bh=(bf16_t*)(sm+32768);   bf16_t* Bl=(bf16_t*)(sm+49152);
  const int lane = tid & 63, wv = tid >> 6;          // 16 waves
  const int wm = (wv >> 2) << 5, wn = (wv & 3) << 5; // 4x4 grid of 32x32
  const bf16_t* gh = Gh + ((size_t)by<<14);
  const bf16_t* gl = Gl + ((size_t)by<<14);
  const bf16_t* th = Th + ((size_t)bx<<14);
  const bf16_t* tl = Tl + ((size_t)bx<<14);
  floatx4 acc[2][2] = {};

#pragma unroll
  for (int kk = 0; kk < 128; kk += 64){
    __syncthreads();
#pragma unroll
    for (int s=0;s<2;s++){
      int idx = tid + (s<<10);              // 0..2047 ushort4 granules
      int row = idx >> 4, cg = idx & 15;
      int off = (row<<6) + (((cg>>1) ^ (row&7))<<3) + ((cg&1)<<2);
      *(ushort4*)&Ah[off] = *(const ushort4*)&gh[(row<<7) + kk + (cg<<2)];
      *(ushort4*)&Al[off] = *(const ushort4*)&gl[(row<<7) + kk + (cg<<2)];
      *(ushort4*)&Bh[off] = *(const ushort4*)&th[(row<<7) + kk + (cg<<2)];
      *(ushort4*)&Bl[off] = *(const ushort4*)&tl[(row<<7) + kk + (cg<<2)];
    }
    __syncthreads();
#pragma unroll
    for (int ks=0; ks<2; ks++){
      int quad = lane>>4, mr = lane&15;
      int c = quad + (ks<<2);
      bf16x8 ah[2], al[2], bh[2], bl[2];
#pragma unroll
      for (int i=0;i<2;i++){
        int rowa = wm + i*16 + mr; int sa = (rowa<<6) + ((c ^ (rowa&7))<<3);
        ah[i] = *(const bf16x8*)&Ah[sa]; al[i] = *(const bf16x8*)&Al[sa];
        int rowb = wn + i*16 + mr; int sb = (rowb<<6) + ((c ^ (rowb&7))<<3);
        bh[i] = *(const bf16x8*)&Bh[sb]; bl[i] = *(const bf16x8*)&Bl[sb];
      }
#pragma unroll
      for (int i=0;i<2;i++)
#pragma unroll
        for (int j=0;j<2;j++){
          acc[i][j] = __builtin_amdgcn_mfma_f32_16x16x32_bf16(ah[i], bl[j], acc[i][j], 0,0,0);
          acc[i][j] = __builtin_amdgcn_mfma_f32_16x16x32_bf16(al[i], bh[j], acc[i][j], 0,0,0);
          acc[i][j] = __builtin_amdgcn_mfma_f32_16x16x32_bf16(ah[i], bh[j], acc[i][j], 0,0,0);
        }
    }
  }
  const int addin = (by != k);
#pragma unroll
  for (int i=0;i<2;i++)
#pragma unroll
    for (int j=0;j<2;j++){
      int rb = (by<<7) + wm + i*16 + ((lane>>4)<<2);
      int col = (bx<<7) + wn + j*16 + (lane&15);
#pragma unroll
      for (int r4=0;r4<4;r4++){
        size_t off = (size_t)(rb+r4)*n + col;
        float v = acc[i][j][r4];
        if (addin) v += Min[off];
        Mout[off] = v;
      }
    }
}

// standalone prep(0): nb blocks x 1024 thr
__global__ __launch_bounds__(1024) void gj_prep0_kernel(
    const float* __restrict__ M, int n,
    bf16_t* Gh, bf16_t* Gl, bf16_t* Th, bf16_t* Tl)
{
  __shared__ char sm[137472] __attribute__((aligned(16)));
  prep1024(M, n, 0, blockIdx.x, Gh, Gl, Th, Tl, sm, threadIdx.x);
}

// fused step: blocks [0,nb) = prep_fused(k+1); blocks [nb, nb+nb*nb) = all
// nb*nb update tiles. One dispatch per GJ step.
__global__ __launch_bounds__(1024) void gj_stepF_kernel(
    const float* __restrict__ Min, float* __restrict__ Mout, int n, int k,
    const bf16_t* __restrict__ Gh, const bf16_t* __restrict__ Gl,
    const bf16_t* __restrict__ Th, const bf16_t* __restrict__ Tl,
    bf16_t* Gnh, bf16_t* Gnl, bf16_t* Tnh, bf16_t* Tnl)
{
  __shared__ char sm[137472] __attribute__((aligned(16)));
  const int nb = n >> 7;
  const int bid = blockIdx.x, tid = threadIdx.x;
  if (bid < nb){
    prep_fused(Min, n, k, bid, Gh, Gl, Th, Tl, Gnh, Gnl, Tnh, Tnl, sm, tid);
  } else {
    int q = bid - nb;
    int by = q / nb, bx = q - by*nb;
    update_tile1024(Min, Mout, n, k, by, bx, Gh, Gl, Th, Tl, sm, tid);
  }
}

// last step: all nb*nb tiles, no prep. grid nb*nb.
__global__ __launch_bounds__(1024) void gj_stepL_kernel(
    const float* __restrict__ Min, float* __restrict__ Mout, int n, int k,
    const bf16_t* __restrict__ Gh, const bf16_t* __restrict__ Gl,
    const bf16_t* __restrict__ Th, const bf16_t* __restrict__ Tl)
{
  __shared__ char sm[65536] __attribute__((aligned(16)));
  const int nb = n >> 7;
  int by = blockIdx.x / nb, bx = blockIdx.x - by*nb;
  update_tile1024(Min, Mout, n, k, by, bx, Gh, Gl, Th, Tl, sm, threadIdx.x);
}

// ---------------------------------------------------------------------------
// Split-K Gram partials: Gp[z][i][j] = sum_{kappa in slice z} V[kappa][i]*V[kappa][j]
// ---------------------------------------------------------------------------
template<int TRANS>
__global__ __launch_bounds__(256) void gram_partial_kernel(
    const float* __restrict__ V, int ldv, int n, int Ks,
    float* __restrict__ Gp)
{
  __shared__ float Vi[16][132];
  __shared__ float Vj[16][132];
  const int cj = blockIdx.x, ci = blockIdx.y, z = blockIdx.z;
  const int tid = threadIdx.x;
  const int i0 = ci<<7, j0 = cj<<7;
  const int tx = tid&15, ty = tid>>4;
  float acc[8][8] = {};
  for (int k0 = z*Ks; k0 < (z+1)*Ks; k0 += 16){
    if (TRANS == 0){
      for (int q=tid; q<512; q+=256){
        int kr = q>>5, c4 = (q&31)<<2;
        *(float4*)&Vi[kr][c4] = *(const float4*)&V[(size_t)(k0+kr)*ldv + i0 + c4];
        *(float4*)&Vj[kr][c4] = *(const float4*)&V[(size_t)(k0+kr)*ldv + j0 + c4];
      }
    } else {
      for (int q=tid; q<512; q+=256){
        int c = q>>2, qq = (q&3)<<2;
        float4 a = *(const float4*)&V[(size_t)(i0+c)*ldv + k0 + qq];
        Vi[qq+0][c]=a.x; Vi[qq+1][c]=a.y; Vi[qq+2][c]=a.z; Vi[qq+3][c]=a.w;
        float4 b = *(const float4*)&V[(size_t)(j0+c)*ldv + k0 + qq];
        Vj[qq+0][c]=b.x; Vj[qq+1][c]=b.y; Vj[qq+2][c]=b.z; Vj[qq+3][c]=b.w;
      }
    }
    __syncthreads();
#pragma unroll
    for (int kr=0; kr<16; kr++){
      float a[8], b[8];
      *(float4*)&a[0] = *(const float4*)&Vi[kr][(ty<<3)];
      *(float4*)&a[4] = *(const float4*)&Vi[kr][(ty<<3)+4];
      *(float4*)&b[0] = *(const float4*)&Vj[kr][(tx<<3)];
      *(float4*)&b[4] = *(const float4*)&Vj[kr][(tx<<3)+4];
#pragma unroll
      for (int i=0;i<8;i++)
#pragma unroll
        for (int jj=0;jj<8;jj++) acc[i][jj] = fmaf(a[i], b[jj], acc[i][jj]);
    }
    __syncthreads();
  }
#pragma unroll
  for (int i=0;i<8;i++)
#pragma unroll
    for (int jj=0;jj<8;jj++)
      Gp[(size_t)z*n*n + (size_t)(i0+(ty<<3)+i)*n + j0+(tx<<3)+jj] = acc[i][jj];
}

// ---------------------------------------------------------------------------
// small kernels
// ---------------------------------------------------------------------------
__global__ void sumsq_kernel(const float* __restrict__ w, int n, float* __restrict__ acc){
  float s = 0.0f;
  for (int i = blockIdx.x*blockDim.x + threadIdx.x; i < n; i += gridDim.x*blockDim.x){
    float v = w[i]; s = fmaf(v, v, s);
  }
#pragma unroll
  for (int o=32;o;o>>=1) s += __shfl_xor(s, o);
  if ((threadIdx.x & 63) == 0) atomicAdd(acc, s);
}

__global__ void scales_kernel(float* scal, const float* a0, const float* a1,
                              const float* a2, const float* a3){
  if (threadIdx.x==0 && blockIdx.x==0){
    float s;
    s = a0[0]/sqrtf(scal[0]); scal[4]=s; scal[8]=s*s;
    s = a1[0]/sqrtf(scal[1]); scal[5]=s; scal[9]=s*s;
    s = a2[0]/sqrtf(scal[2]); scal[6]=s; scal[10]=s*s;
    s = a3[0]/sqrtf(scal[3]); scal[7]=s; scal[11]=s*s;
  }
}

__global__ void build_mm_kernel(const float* __restrict__ W, const float* __restrict__ scal,
                                float* __restrict__ Mo){
  int j = (blockIdx.x<<4) + (threadIdx.x&15);
  int i = (blockIdx.y<<4) + (threadIdx.x>>4);
  float s = scal[5];
  float a = s*(W[((size_t)i<<12)+j] - W[((size_t)j<<12)+i]);
  Mo[((size_t)i<<12)+j] = ((i==j)?1.0f:0.0f) + a;
}

// Mo = I + s*(W - W^T) + s2 * sum_s Gp[s]
__global__ void build_rect_kernel(const float* __restrict__ W, int ldw, int transw, int n,
      const float* __restrict__ Gp, int S,
      const float* __restrict__ scal, int sidx, int sidx2,
      float* __restrict__ Mo){
  int j = (blockIdx.x<<4)+(threadIdx.x&15);
  int i = (blockIdx.y<<4)+(threadIdx.x>>4);
  float s = scal[sidx], s2 = scal[sidx2];
  float wij = transw ? W[(size_t)j*ldw+i] : W[(size_t)i*ldw+j];
  float wji = transw ? W[(size_t)i*ldw+j] : W[(size_t)j*ldw+i];
  float g = 0.0f;
  for (int ss=0; ss<S; ss++) g += Gp[(size_t)ss*n*n + (size_t)i*n + j];
  Mo[(size_t)i*n + j] = ((i==j)?1.0f:0.0f) + s*(wij - wji) + s2*g;
}

// dst = 2*X - I
template<typename TD>
__global__ void qtop_kernel(const float* __restrict__ X, int n,
                            TD* __restrict__ dst, int ldd){
  int j = blockIdx.x*blockDim.x + threadIdx.x;
  int i = blockIdx.y;
  if (j<n) storeS(&dst[(size_t)i*ldd+j],
                  2.0f*X[(size_t)i*n+j] - ((i==j)?1.0f:0.0f));
}

// fp32 tiled transpose: dst[c][r] = src[r][c]; rows,cols % 32 == 0
__global__ void transposeF_kernel(const float* __restrict__ src, int ls,
                                  float* __restrict__ dst, int ld){
  __shared__ float t[32][33];
  int c0 = blockIdx.x<<5, r0 = blockIdx.y<<5;
  int tx = threadIdx.x & 31, ty = threadIdx.x >> 5;
#pragma unroll
  for (int i=0;i<4;i++) t[ty+i*8][tx] = src[(size_t)(r0+ty+i*8)*ls + c0+tx];
  __syncthreads();
#pragma unroll
  for (int i=0;i<4;i++) dst[(size_t)(c0+ty+i*8)*ld + r0+tx] = t[tx][ty+i*8];
}

// A' = [ bf16(h) | bf16(x) | bf16(x - bf16(x)) ]  (8192 x 2176)
__global__ void pack_A_kernel(const float* __restrict__ h, const float* __restrict__ x,
                              bf16_t* __restrict__ Ap){
  int c = blockIdx.x*blockDim.x + threadIdx.x;
  int m = blockIdx.y;
  if (c >= 2176) return;
  float v;
  if (c < 128)       v = h[(size_t)m*128 + c];
  else if (c < 1152) v = x[(size_t)m*1024 + (c-128)];
  else {
    float xv = x[(size_t)m*1024 + (c-1152)];
    v = xv - bf2f(f2bf(xv));
  }
  Ap[(size_t)m*2176 + c] = f2bf(v);
}

__global__ void dup_kernel(bf16_t* __restrict__ Bp){
  int c = blockIdx.x*blockDim.x + threadIdx.x;   // 0..1023
  int r = blockIdx.y;
  Bp[(size_t)r*2176 + 1152 + c] = Bp[(size_t)r*2176 + 128 + c];
}

__global__ void addvec_kernel(const float* __restrict__ a, const float* __restrict__ b,
                              float* __restrict__ c, int n){
  int i = blockIdx.x*blockDim.x + threadIdx.x;
  if (i<n) c[i] = a[i] + b[i];
}

// simplex-with-floor projection: one wave per row of 128; 30 Newton iters.
__global__ __launch_bounds__(256) void project_kernel(
    const float* __restrict__ ft, const float* __restrict__ h, float* __restrict__ out){
  int row  = (blockIdx.x<<2) + (threadIdx.x>>6);
  int lane = threadIdx.x & 63;
  const float* fr = ft + ((size_t)row<<7);
  const float* hr = h  + ((size_t)row<<7);
  float f0 = fr[lane], f1 = fr[lane+64];
  float l0 = -ALPHA_1*(expf(SIGMA_1*hr[lane])   - 1.0f);
  float l1 = -ALPHA_1*(expf(SIGMA_1*hr[lane+64])- 1.0f);
  float s = f0 + f1;
#pragma unroll
  for (int o=32;o;o>>=1) s += __shfl_xor(s, o);
  float lam = s * (1.0f/128.0f);
  for (int it=0; it<30; it++){
    float a0 = f0 - lam, a1 = f1 - lam;
    float g = fmaxf(a0,l0) + fmaxf(a1,l1);
    float c = (a0>l0 ? 1.0f:0.0f) + (a1>l1 ? 1.0f:0.0f);
#pragma unroll
    for (int o=32;o;o>>=1){ g += __shfl_xor(g,o); c += __shfl_xor(c,o); }
    lam += g / fmaxf(c, 1.0f);
  }
  out[((size_t)row<<7)+lane]    = fmaxf(f0-lam, l0);
  out[((size_t)row<<7)+lane+64] = fmaxf(f1-lam, l1);
}

// ---------------------------------------------------------------------------
// host-side helpers (enqueue only)
// ---------------------------------------------------------------------------
template<typename TC, int RELU>
static inline void mfma_nt(hipStream_t st, int Mm, int Nn, int Kk,
    const bf16_t* A, int lda, const bf16_t* B, int ldb, TC* C, int ldc,
    const float* bias){
  dim3 grid(Nn>>7, Mm>>7);
  mfma_nt_kernel<TC,RELU><<<grid, 256, 0, st>>>(Mm,Nn,Kk,A,lda,B,ldb,C,ldc,bias);
}

template<typename TC>
static inline void fgemm(hipStream_t st, int Mm, int Nn, int Kk,
    const float* A, int lda, const float* Bt, int ldb, TC* C, int ldc,
    float alpha, const float* aptr, float beta){
  dim3 grid(Nn>>7, Mm>>7);
  fgemm_nt_kernel<TC><<<grid, 256, 0, st>>>(Mm,Nn,Kk,A,lda,Bt,ldb,C,ldc,
                                            alpha,aptr,beta, 1<<30);
}

// Ping-pong block Gauss-Jordan inverse; nb even -> result lands back in M.
// prep0; then ONE fused dispatch per step; last step stepL.
static void gj_inverse5(hipStream_t st, float* M, float* Mtmp, int n,
    bf16_t* Gh, bf16_t* Gl, bf16_t* Th, bf16_t* Tl){
  const int nb = n >> 7;
  const size_t gstep = (size_t)nb << 14;
  gj_prep0_kernel<<<nb, 1024, 0, st>>>(M, n, Gh, Gl, Th, Tl);   // parity 0
  for (int k=0; k<nb; k++){
    const float* Min = (k&1) ? Mtmp : M;
    float* Mout      = (k&1) ? M : Mtmp;
    const size_t pc = (size_t)(k&1)*gstep, pn = (size_t)((k&1)^1)*gstep;
    if (k < nb-1){
      gj_stepF_kernel<<<nb + nb*nb, 1024, 0, st>>>(Min, Mout, n, k,
          Gh+pc, Gl+pc, Th+pc, Tl+pc,
          Gh+pn, Gl+pn, Th+pn, Tl+pn);
    } else {
      gj_stepL_kernel<<<nb*nb, 1024, 0, st>>>(Min, Mout, n, k,
          Gh+pc, Gl+pc, Th+pc, Tl+pc);
    }
  }
}

extern "C" void kernel_launch(void* const* d_in, const int* in_sizes, int n_in,
                              void* d_out, int out_size, void* d_ws, size_t ws_size,
                              hipStream_t stream){
  (void)in_sizes; (void)n_in; (void)out_size; (void)ws_size;
  const float* h    = (const float*)d_in[0];   // 8192x128
  const float* x    = (const float*)d_in[1];   // 8192x1024
  const float* Whm  = (const float*)d_in[2];   // 4096x128
  const float* bhm  = (const float*)d_in[3];
  const float* ahm  = (const float*)d_in[4];
  const float* Wmm  = (const float*)d_in[5];   // 4096x4096
  const float* bmm  = (const float*)d_in[6];
  const float* amm  = (const float*)d_in[7];
  const float* Wmh  = (const float*)d_in[8];   // 128x4096
  const float* bmh  = (const float*)d_in[9];
  const float* amh  = (const float*)d_in[10];
  const float* Wux  = (const float*)d_in[11];  // 4096x1024
  const float* bux  = (const float*)d_in[12];
  const float* auxs = (const float*)d_in[13];
  float* out = (float*)d_out;

  // ---- workspace (~188 MiB peak; 189 MiB proven safe) ----
  char* wp = (char*)d_ws;
  auto alloc = [&](size_t bytes)->void*{
    void* p = (void*)wp; wp += (bytes + 255) & ~(size_t)255; return p; };
  float*  scal   = (float*)alloc(4096);
  float*  Mhm    = (float*)alloc((size_t)128*128*4);
  float*  Mmh    = (float*)alloc((size_t)128*128*4);
  float*  P128   = (float*)alloc((size_t)128*128*4);
  float*  PT128  = (float*)alloc((size_t)128*128*4);
  bf16_t* GhB    = (bf16_t*)alloc((size_t)2*32*16384*2);  // 2 MiB (2 parities)
  bf16_t* GlB    = (bf16_t*)alloc((size_t)2*32*16384*2);  // 2 MiB
  bf16_t* ThB    = (bf16_t*)alloc((size_t)2*32*16384*2);  // 2 MiB
  bf16_t* TlB    = (bf16_t*)alloc((size_t)2*32*16384*2);  // 2 MiB
  bf16_t* Qmh_b  = (bf16_t*)alloc((size_t)128*4096*2);    // 1 MiB
  float*  bsum   = (float*)alloc((size_t)4096*4);
  bf16_t* Bp     = (bf16_t*)alloc((size_t)4096*2176*2);   // 17 MiB [Qhm|Qux|Qux_dup]
  float*  R1     = (float*)alloc((size_t)4096*4096*4);    // 64 MiB
  float*  R2     = (float*)alloc((size_t)4096*4096*4);    // 64 MiB
  bf16_t* Qmmb   = (bf16_t*)alloc((size_t)4096*4096*2);   // 32 MiB
  // lifetime aliases:
  float*  gram23 = R1;                          // phases 2/3: 31 Gram partials (~2 MiB)
  float*  WmhTv  = R1 + (size_t)1024*1024;      // phase 3: 3968x128 (disjoint)
  float*  Mmm  = R1;                            // I+A_mm -> inverse (GJ ping-pong R1<->R2)
  bf16_t* Ap   = (bf16_t*)R1;                   // packed A' (after qtop)
  bf16_t* z2   = (bf16_t*)R1;                   // GEMM2 out
  float*  Mux  = R2 + (size_t)1024*1024;        // phase-1 carve of R2
  float*  XuxT = R2 + (size_t)5*1024*1024;      //   4 MiB
  float*  Gp1  = R2 + (size_t)6*1024*1024;      //   16 MiB (4 split-K Gram partials)
  bf16_t* z    = (bf16_t*)R2;                   // GEMM1 out
  float*  ftl  = R2;                            // GEMM3 out (z dead)

  // ---- phase 0: scales s = a/||W||_F
  hipMemsetAsync(scal, 0, 16*sizeof(float), stream);
  sumsq_kernel<<<512,256,0,stream>>>(Whm, 4096*128,  scal+0);
  sumsq_kernel<<<512,256,0,stream>>>(Wmm, 4096*4096, scal+1);
  sumsq_kernel<<<512,256,0,stream>>>(Wmh, 128*4096,  scal+2);
  sumsq_kernel<<<512,256,0,stream>>>(Wux, 4096*1024, scal+3);
  scales_kernel<<<1,1,0,stream>>>(scal, ahm, amm, amh, auxs);

  // ---- phase 1: ux (1024) -> Bp cols [128,1152)
  gram_partial_kernel<0><<<dim3(8,8,4),256,0,stream>>>(
      Wux + (size_t)1024*1024, 1024, 1024, 768, Gp1);     // V = Wux[1024:]
  build_rect_kernel<<<dim3(64,64),256,0,stream>>>(Wux,1024,0,1024, Gp1,4, scal,7,11, Mux);
  gj_inverse5(stream, Mux, R1, 1024, GhB, GlB, ThB, TlB);
  transposeF_kernel<<<dim3(32,32),256,0,stream>>>(Mux, 1024, XuxT, 1024);
  qtop_kernel<bf16_t><<<dim3(4,1024),256,0,stream>>>(Mux, 1024, Bp+128, 2176);
  fgemm<bf16_t>(stream, 3072,1024,1024, Wux+(size_t)1024*1024,1024, XuxT,1024,
                Bp+(size_t)1024*2176+128, 2176, -2.0f,&scal[7], 0.0f);

  // ---- phase 2: hm (128) -> Bp cols [0,128)
  gram_partial_kernel<0><<<dim3(1,1,31),256,0,stream>>>(
      Whm + (size_t)128*128, 128, 128, 128, gram23);      // V = Whm[128:]
  build_rect_kernel<<<dim3(8,8),256,0,stream>>>(Whm,128,0,128, gram23,31, scal,4,8, Mhm);
  invert128_kernel<<<1,1024,0,stream>>>(Mhm,128,P128,PT128);
  qtop_kernel<bf16_t><<<dim3(1,128),256,0,stream>>>(P128, 128, Bp, 2176);
  fgemm<bf16_t>(stream, 3968,128,128, Whm+128*128,128, PT128,128,
                Bp+(size_t)128*2176, 2176, -2.0f,&scal[4], 0.0f);

  // ---- phase 3: mh (via W_mh^T) -> Qmh_b (128x4096)
  gram_partial_kernel<1><<<dim3(1,1,31),256,0,stream>>>(
      Wmh + 128, 4096, 128, 128, gram23);                 // V[kap][i]=Wmh[i][128+kap]
  build_rect_kernel<<<dim3(8,8),256,0,stream>>>(Wmh,4096,1,128, gram23,31, scal,6,10, Mmh);
  invert128_kernel<<<1,1024,0,stream>>>(Mmh,128,P128,PT128);
  qtop_kernel<bf16_t><<<dim3(1,128),256,0,stream>>>(PT128, 128, Qmh_b, 4096);
  transposeF_kernel<<<dim3(124,4),256,0,stream>>>(Wmh+128, 4096, WmhTv, 128);
  fgemm<bf16_t>(stream, 128,3968,128, PT128,128, WmhTv,128,
                Qmh_b+128, 4096, -2.0f,&scal[6], 0.0f);

  // ---- phase 4: mm (4096): GJ inverse ping-pong R1<->R2, then Q = 2X - I
  build_mm_kernel<<<dim3(256,256),256,0,stream>>>(Wmm, scal, Mmm);
  gj_inverse5(stream, Mmm, R2, 4096, GhB, GlB, ThB, TlB);
  qtop_kernel<bf16_t><<<dim3(16,4096),256,0,stream>>>(Mmm, 4096, Qmmb, 4096);
  // R1 now dead -> Ap; R2 free -> z.

  // ---- phase 5: pack A', finish B', bias sum
  pack_A_kernel<<<dim3(9,8192),256,0,stream>>>(h, x, Ap);
  dup_kernel<<<dim3(4,4096),256,0,stream>>>(Bp);
  addvec_kernel<<<16,256,0,stream>>>(bhm, bux, bsum, 4096);

  // ---- phases 6-8: forward (bf16 MFMA)
  mfma_nt<bf16_t,1>(stream, 8192,4096,2176, Ap,2176, Bp,2176, z,4096, bsum);
  mfma_nt<bf16_t,1>(stream, 8192,4096,4096, z,4096, Qmmb,4096, z2,4096, bmm);
  mfma_nt<float,0>(stream, 8192, 128,4096, z2,4096, Qmh_b,4096, ftl,128, bmh);

  // ---- phase 9: projection
  project_kernel<<<2048,256,0,stream>>>(ftl, h, out);
}